// Round 12
// baseline (1954.761 us; speedup 1.0000x reference)
//
#include <hip/hip_runtime.h>

#define BATCH 512
#define TLEN 128
#define DIN 512
#define HID 256
#define NCLS 96
#define STEPS 26
#define GRUIN 608
#define G3 768

#define BM 64
#define BN 64
#define BK 16
#define LDS_STRIDE 68

typedef unsigned short ushort_t;
typedef __attribute__((ext_vector_type(8))) short short8v;
typedef __attribute__((ext_vector_type(4))) float f32x4;
typedef __attribute__((ext_vector_type(8))) unsigned short ushort8v;

__device__ __forceinline__ float fast_tanh(float x) {
    return 1.f - 2.f / (__expf(2.f * x) + 1.f);
}
__device__ __forceinline__ float fast_sigmoid(float x) {
    return 1.f / (1.f + __expf(-x));
}
__device__ __forceinline__ ushort_t f2bf_rne(float f) {
    unsigned int u = __float_as_uint(f);
    unsigned int r = (u + 0x7FFFu + ((u >> 16) & 1u)) >> 16;
    return (ushort_t)r;
}
__device__ __forceinline__ float bf2f(ushort_t h) {
    return __uint_as_float(((unsigned int)h) << 16);
}

// ================= one-time prep =================
// Wih16 bf16 [768][512] = W_ih[:, :512]; Wi2h16 bf16 [256][512];
// Wcat16 bf16 [1024][256] (row n, col k); WembT fp32 [96][768];
// Wgen16 bf16 [96][256]; bcat[1024]; hidden=0; hg0 = bcat broadcast.
__global__ __launch_bounds__(256)
void prep_all(const float* __restrict__ W_h2h, const float* __restrict__ W_hh,
              const float* __restrict__ W_ih, const float* __restrict__ W_i2h,
              const float* __restrict__ b_ih, const float* __restrict__ b_h2h,
              const float* __restrict__ b_hh, const float* __restrict__ W_gen,
              ushort_t* __restrict__ Wih16, ushort_t* __restrict__ Wi2h16,
              ushort_t* __restrict__ Wcat16, float* __restrict__ WembT,
              ushort_t* __restrict__ Wgen16, float* __restrict__ bcat,
              float* __restrict__ hidden, float* __restrict__ hg) {
    int idx = blockIdx.x * 256 + threadIdx.x;
    if (idx < 393216) {
        int r = idx >> 9, c = idx & 511;
        Wih16[idx] = f2bf_rne(W_ih[(size_t)r * GRUIN + c]);
    } else if (idx < 393216 + 131072) {
        int j = idx - 393216;
        Wi2h16[j] = f2bf_rne(W_i2h[j]);
    } else if (idx < 393216 + 131072 + 262144) {
        int j = idx - (393216 + 131072);
        int n = j >> 8, k = j & 255;
        float v = (n < 256) ? W_h2h[n * 256 + k] : W_hh[(size_t)(n - 256) * 256 + k];
        Wcat16[j] = f2bf_rne(v);
    } else if (idx < 393216 + 131072 + 262144 + 73728) {
        int j = idx - (393216 + 131072 + 262144);
        int ch = j / 768, jj = j - ch * 768;
        WembT[j] = W_ih[(size_t)jj * GRUIN + 512 + ch] + b_ih[jj];
    } else if (idx < 393216 + 131072 + 262144 + 73728 + 24576) {
        int j = idx - (393216 + 131072 + 262144 + 73728);
        Wgen16[j] = f2bf_rne(W_gen[j]);
    } else if (idx < 393216 + 131072 + 262144 + 73728 + 24576 + 1024) {
        int j = idx - (393216 + 131072 + 262144 + 73728 + 24576);
        bcat[j] = (j < 256) ? b_h2h[j] : b_hh[j - 256];
    } else if (idx < 393216 + 131072 + 262144 + 73728 + 24576 + 1024 + 131072) {
        int j = idx - (393216 + 131072 + 262144 + 73728 + 24576 + 1024);
        hidden[j] = 0.f;
    } else if (idx < 393216 + 131072 + 262144 + 73728 + 24576 + 1024 + 131072 + 524288) {
        int j = idx - (393216 + 131072 + 262144 + 73728 + 24576 + 1024 + 131072);
        int c = j & 1023;
        hg[j] = (c < 256) ? b_h2h[c] : b_hh[c - 256];
    }
}

// ================= batch_H fp32 -> bf16 =================
__global__ __launch_bounds__(256)
void conv_a16(const float* __restrict__ src, ushort_t* __restrict__ dst, int n8) {
    int i = blockIdx.x * 256 + threadIdx.x;
    const int stride = gridDim.x * 256;
    for (; i < n8; i += stride) {
        float4 v0 = ((const float4*)src)[2 * i];
        float4 v1 = ((const float4*)src)[2 * i + 1];
        ushort8v o;
        o[0] = f2bf_rne(v0.x); o[1] = f2bf_rne(v0.y);
        o[2] = f2bf_rne(v0.z); o[3] = f2bf_rne(v0.w);
        o[4] = f2bf_rne(v1.x); o[5] = f2bf_rne(v1.y);
        o[6] = f2bf_rne(v1.z); o[7] = f2bf_rne(v1.w);
        ((ushort8v*)dst)[i] = o;
    }
}

// LDS swizzle (validated in rounds 10-11): dense 32-ushort rows, XOR quad index
__device__ __forceinline__ int swz(int row, int col8) {
    return (row * 32 + col8 * 8) ^ ((row & 7) << 3);
}

// ================= Hp GEMM: Hp16[65536,256] = A16 @ Wi2h16^T =================
__global__ __launch_bounds__(256)
void hp_mfma(const ushort_t* __restrict__ A16,
             const ushort_t* __restrict__ B16,    // [256][512]
             ushort_t* __restrict__ Hp16) {
    __shared__ ushort_t As[128 * 32];
    __shared__ ushort_t Bs[128 * 32];
    const int id = (blockIdx.x & 7) * 128 + (blockIdx.x >> 3);  // bijective XCD map
    const int mt = id >> 1, nt = id & 1;
    const int bm = mt * 128, bn = nt * 128;
    const int tid = threadIdx.x;
    const int wid = tid >> 6, lane = tid & 63;
    const int wr = wid >> 1, wc = wid & 1;
    const int sr = tid >> 2, sq = tid & 3;
    f32x4 acc[4][4] = {};
    const int l15 = lane & 15, lhi = lane >> 4;
    for (int k0 = 0; k0 < 512; k0 += 32) {
        ushort8v a0 = *(const ushort8v*)(A16 + (size_t)(bm + sr) * 512 + k0 + sq * 8);
        ushort8v a1 = *(const ushort8v*)(A16 + (size_t)(bm + sr + 64) * 512 + k0 + sq * 8);
        ushort8v b0 = *(const ushort8v*)(B16 + (size_t)(bn + sr) * 512 + k0 + sq * 8);
        ushort8v b1 = *(const ushort8v*)(B16 + (size_t)(bn + sr + 64) * 512 + k0 + sq * 8);
        __syncthreads();
        *(ushort8v*)(&As[swz(sr, sq)]) = a0;
        *(ushort8v*)(&As[swz(sr + 64, sq)]) = a1;
        *(ushort8v*)(&Bs[swz(sr, sq)]) = b0;
        *(ushort8v*)(&Bs[swz(sr + 64, sq)]) = b1;
        __syncthreads();
        short8v af[4], bfr[4];
#pragma unroll
        for (int i = 0; i < 4; ++i) {
            int arow = wr * 64 + i * 16 + l15;
            af[i] = *(const short8v*)(&As[swz(arow, lhi)]);
            int brow = wc * 64 + i * 16 + l15;
            bfr[i] = *(const short8v*)(&Bs[swz(brow, lhi)]);
        }
#pragma unroll
        for (int i = 0; i < 4; ++i)
#pragma unroll
            for (int j = 0; j < 4; ++j)
                acc[i][j] = __builtin_amdgcn_mfma_f32_16x16x32_bf16(af[i], bfr[j], acc[i][j], 0, 0, 0);
    }
    const int cr0 = bm + wr * 64 + lhi * 4;
    const int cc0 = bn + wc * 64 + l15;
#pragma unroll
    for (int i = 0; i < 4; ++i)
#pragma unroll
        for (int j = 0; j < 4; ++j)
#pragma unroll
            for (int p = 0; p < 4; ++p)
                Hp16[(size_t)(cr0 + i * 16 + p) * 256 + cc0 + j * 16] = f2bf_rne(acc[i][j][p]);
}

// ================= per-step: scores + softmax + context =================
__global__ __launch_bounds__(1024)
void step_attn(const ushort_t* __restrict__ Hp16,  // [M][256] bf16
               const ushort_t* __restrict__ bH16,  // [M][512] bf16
               const float* __restrict__ hg,       // [512][1024]
               const float* __restrict__ Wscore,
               ushort_t* __restrict__ ctx16) {     // [512][512] bf16
    const int b = blockIdx.x;
    const int tid = threadIdx.x;   // 1024 = 16 waves
    const int w = tid >> 6, lane = tid & 63;
    __shared__ __align__(16) float hp[HID];
    __shared__ __align__(16) float wsc[HID];
    __shared__ __align__(16) float parts[16][512];  // storage-transposed: [w][k*64+lane]
    __shared__ float es[TLEN];
    __shared__ float al[TLEN];
    __shared__ float red[16];

    const size_t rowbase = (size_t)b * TLEN;
    if (tid < 256) {
        hp[tid] = hg[(size_t)b * 1024 + tid];
        wsc[tid] = Wscore[tid];
    }
    __syncthreads();
    // scores: wave per t, 8 iters
#pragma unroll
    for (int i = 0; i < 8; ++i) {
        int t = i * 16 + w;
        ushort4 hv = *(const ushort4*)(Hp16 + (rowbase + t) * 256 + lane * 4);
        float4 hpv = *(const float4*)(&hp[lane * 4]);
        float4 wv = *(const float4*)(&wsc[lane * 4]);
        float sc = fast_tanh(bf2f(hv.x) + hpv.x) * wv.x
                 + fast_tanh(bf2f(hv.y) + hpv.y) * wv.y
                 + fast_tanh(bf2f(hv.z) + hpv.z) * wv.z
                 + fast_tanh(bf2f(hv.w) + hpv.w) * wv.w;
#pragma unroll
        for (int off = 32; off >= 1; off >>= 1) sc += __shfl_xor(sc, off);
        if (lane == 0) es[t] = sc;
    }
    __syncthreads();
    // softmax (threads 0..127 = waves 0,1)
    float ev = 0.f, p = 0.f;
    if (tid < TLEN) {
        ev = es[tid];
        float mx = ev;
#pragma unroll
        for (int off = 32; off >= 1; off >>= 1) mx = fmaxf(mx, __shfl_xor(mx, off));
        if (lane == 0) red[w] = mx;
    }
    __syncthreads();
    if (tid < TLEN) {
        float m = fmaxf(red[0], red[1]);
        p = __expf(ev - m);
        float sm = p;
#pragma unroll
        for (int off = 32; off >= 1; off >>= 1) sm += __shfl_xor(sm, off);
        if (lane == 0) red[8 + w] = sm;
    }
    __syncthreads();
    if (tid < TLEN) al[tid] = p / (red[8] + red[9]);
    __syncthreads();
    // context: wave w accumulates its 8 t's; lane owns cols lane*8..+7 (16B loads)
    {
        float a0 = 0.f, a1 = 0.f, a2 = 0.f, a3 = 0.f;
        float a4 = 0.f, a5 = 0.f, a6 = 0.f, a7 = 0.f;
#pragma unroll
        for (int i = 0; i < 8; ++i) {
            int t = i * 16 + w;
            ushort8v v = *(const ushort8v*)(bH16 + (rowbase + t) * 512 + lane * 8);
            float a = al[t];
            a0 = fmaf(a, bf2f(v[0]), a0);
            a1 = fmaf(a, bf2f(v[1]), a1);
            a2 = fmaf(a, bf2f(v[2]), a2);
            a3 = fmaf(a, bf2f(v[3]), a3);
            a4 = fmaf(a, bf2f(v[4]), a4);
            a5 = fmaf(a, bf2f(v[5]), a5);
            a6 = fmaf(a, bf2f(v[6]), a6);
            a7 = fmaf(a, bf2f(v[7]), a7);
        }
        // conflict-free transposed store: storage idx = k*64 + lane
        parts[w][0 * 64 + lane] = a0;
        parts[w][1 * 64 + lane] = a1;
        parts[w][2 * 64 + lane] = a2;
        parts[w][3 * 64 + lane] = a3;
        parts[w][4 * 64 + lane] = a4;
        parts[w][5 * 64 + lane] = a5;
        parts[w][6 * 64 + lane] = a6;
        parts[w][7 * 64 + lane] = a7;
    }
    __syncthreads();
    if (tid < 512) {
        float ssum = 0.f;
#pragma unroll
        for (int k = 0; k < 16; ++k) ssum += parts[k][tid];
        int col = (tid & 63) * 8 + (tid >> 6);   // storage idx -> actual column
        ctx16[(size_t)b * 512 + col] = f2bf_rne(ssum);
    }
}

// ================= per-step: gi GEMM + GRU + generator + hg GEMM (16 blocks x 32 rows) =================
__global__ __launch_bounds__(512)
void gigru_hg(const ushort_t* __restrict__ ctx16,  // [512][512] bf16
              const ushort_t* __restrict__ Wih16,  // [768][512] bf16
              const ushort_t* __restrict__ Wcat16, // [1024][256] bf16
              const ushort_t* __restrict__ Wgen16, // [96][256] bf16
              const float* __restrict__ WembT,     // [96][768]
              const float* __restrict__ bcat,      // [1024]
              const float* __restrict__ b_gen,     // [96]
              const int* __restrict__ text,
              int s,
              float* __restrict__ gi_g,            // [512][768]
              float* __restrict__ hg_g,            // [512][1024] in/out
              float* __restrict__ hidden,          // [512][256] in/out
              float* __restrict__ out) {
    __shared__ __align__(16) ushort_t ctxs[32 * 512];  // 32 KB, swizzled
    __shared__ __align__(16) ushort_t hs[32 * 256];    // 16 KB, swizzled
    const int rb = blockIdx.x * 32;
    const int tid = threadIdx.x;   // 512 = 8 waves
    const int w = tid >> 6, lane = tid & 63;
    const int l15 = lane & 15, lhi = lane >> 4;

    // stage context rows (coalesced; swizzled dest)
#pragma unroll
    for (int j = 0; j < 4; ++j) {
        int q = j * 512 + tid;
        int row = q >> 6, cq = q & 63;
        ushort8v v = *(const ushort8v*)(ctx16 + (size_t)(rb + row) * 512 + cq * 8);
        *(ushort8v*)(&ctxs[row * 512 + ((cq ^ (row & 7)) << 3)]) = v;
    }
    __syncthreads();

    // ---- gi GEMM: 32x768, K=512; wave w -> n-tiles w+8j
    {
        f32x4 accg[6][2] = {};
#pragma unroll 2
        for (int kk = 0; kk < 16; ++kk) {
            int ar0 = l15;           // mt=0 row
            int ar1 = 16 + l15;      // mt=1 row
            short8v af0 = *(const short8v*)(&ctxs[ar0 * 512 + (((kk * 4 + lhi) ^ (ar0 & 7)) << 3)]);
            short8v af1 = *(const short8v*)(&ctxs[ar1 * 512 + (((kk * 4 + lhi) ^ (ar1 & 7)) << 3)]);
#pragma unroll
            for (int j = 0; j < 6; ++j) {
                int nt = w + 8 * j;
                short8v bf = *(const short8v*)(Wih16 + (size_t)(nt * 16 + l15) * 512 + kk * 32 + lhi * 8);
                accg[j][0] = __builtin_amdgcn_mfma_f32_16x16x32_bf16(af0, bf, accg[j][0], 0, 0, 0);
                accg[j][1] = __builtin_amdgcn_mfma_f32_16x16x32_bf16(af1, bf, accg[j][1], 0, 0, 0);
            }
        }
#pragma unroll
        for (int j = 0; j < 6; ++j) {
            int nt = w + 8 * j;
#pragma unroll
            for (int mt = 0; mt < 2; ++mt)
#pragma unroll
                for (int p = 0; p < 4; ++p)
                    gi_g[(size_t)(rb + mt * 16 + lhi * 4 + p) * 768 + nt * 16 + l15] = accg[j][mt][p];
        }
    }
    __syncthreads();

    // ---- GRU: 32 rows x 256 (16 items/thread); writes hidden fp32 + hs bf16 (swizzled)
#pragma unroll 4
    for (int it = 0; it < 16; ++it) {
        int idx = it * 512 + tid;
        int row = idx >> 8, h = idx & 255;
        int b = rb + row;
        int ch = text[b * STEPS + s];
        const float* em = WembT + (size_t)ch * G3;
        const float* gib = gi_g + (size_t)b * G3;
        const float* ghb = hg_g + (size_t)b * 1024 + 256;
        float ir = gib[h] + em[h] + ghb[h];
        float iz = gib[256 + h] + em[256 + h] + ghb[256 + h];
        float in_ = gib[512 + h] + em[512 + h];
        float hn = ghb[512 + h];
        float rr = fast_sigmoid(ir);
        float zz = fast_sigmoid(iz);
        float nn = fast_tanh(in_ + rr * hn);
        float nh = (1.f - zz) * nn + zz * hidden[(size_t)b * HID + h];
        hidden[(size_t)b * HID + h] = nh;
        int q = h >> 3;
        hs[row * 256 + ((q ^ (row & 7)) << 3) + (h & 7)] = f2bf_rne(nh);
    }
    __syncthreads();

    // ---- generator: 32x96, K=256; waves 0..5
    if (w < 6) {
        int nt = w;
#pragma unroll
        for (int mt = 0; mt < 2; ++mt) {
            f32x4 acc = {};
#pragma unroll
            for (int kk = 0; kk < 8; ++kk) {
                int arow = mt * 16 + l15;
                short8v af = *(const short8v*)(&hs[arow * 256 + (((kk * 4 + lhi) ^ (arow & 7)) << 3)]);
                short8v bf = *(const short8v*)(Wgen16 + (size_t)(nt * 16 + l15) * 256 + kk * 32 + lhi * 8);
                acc = __builtin_amdgcn_mfma_f32_16x16x32_bf16(af, bf, acc, 0, 0, 0);
            }
#pragma unroll
            for (int p = 0; p < 4; ++p) {
                int row = rb + mt * 16 + lhi * 4 + p;
                int col = nt * 16 + l15;
                out[((size_t)row * STEPS + s) * NCLS + col] = acc[p] + b_gen[col];
            }
        }
    }

    // ---- hg GEMM for next step: 32x1024, K=256 (skip on last step)
    if (s < STEPS - 1) {
        f32x4 acch[8][2] = {};
#pragma unroll
        for (int kk = 0; kk < 8; ++kk) {
            int ar0 = l15;
            int ar1 = 16 + l15;
            short8v af0 = *(const short8v*)(&hs[ar0 * 256 + (((kk * 4 + lhi) ^ (ar0 & 7)) << 3)]);
            short8v af1 = *(const short8v*)(&hs[ar1 * 256 + (((kk * 4 + lhi) ^ (ar1 & 7)) << 3)]);
#pragma unroll
            for (int j = 0; j < 8; ++j) {
                int nt = w + 8 * j;
                short8v bf = *(const short8v*)(Wcat16 + (size_t)(nt * 16 + l15) * 256 + kk * 32 + lhi * 8);
                acch[j][0] = __builtin_amdgcn_mfma_f32_16x16x32_bf16(af0, bf, acch[j][0], 0, 0, 0);
                acch[j][1] = __builtin_amdgcn_mfma_f32_16x16x32_bf16(af1, bf, acch[j][1], 0, 0, 0);
            }
        }
#pragma unroll
        for (int j = 0; j < 8; ++j) {
            int nt = w + 8 * j;
#pragma unroll
            for (int mt = 0; mt < 2; ++mt)
#pragma unroll
                for (int p = 0; p < 4; ++p) {
                    int row = rb + mt * 16 + lhi * 4 + p;
                    int col = nt * 16 + l15;
                    hg_g[(size_t)row * 1024 + col] = acch[j][mt][p] + bcat[col];
                }
        }
    }
}

// ================= fallback kernels (round-3 Plan B, validated) =================
template <typename OutT>
__device__ __forceinline__ void store_c(OutT* p, float v);
template <> __device__ __forceinline__ void store_c<float>(float* p, float v) { *p = v; }
template <> __device__ __forceinline__ void store_c<ushort_t>(ushort_t* p, float v) { *p = f2bf_rne(v); }

template <typename OutT>
__global__ __launch_bounds__(256)
void gemm_nt(const float* __restrict__ A, int lda,
             const float* __restrict__ Bw, int ldb,
             OutT* __restrict__ Cc, int ldc,
             const float* __restrict__ bias,
             int M, int N, int K) {
    __shared__ float As[BK][LDS_STRIDE];
    __shared__ float Bs[BK][LDS_STRIDE];
    const int tid = threadIdx.x;
    const int bm = blockIdx.x * BM;
    const int bn = blockIdx.y * BN;
    const int tx = tid & 15, ty = tid >> 4;
    const int lr = tid >> 2;
    const int lc = (tid & 3) << 2;
    float acc[4][4] = {};
    const int gr = bm + lr;
    const int gn = bn + lr;
    const float* Arow = A + (size_t)gr * lda;
    const float* Brow = Bw + (size_t)gn * ldb;
    for (int k0 = 0; k0 < K; k0 += BK) {
        float4 va = make_float4(0.f, 0.f, 0.f, 0.f);
        float4 vb = make_float4(0.f, 0.f, 0.f, 0.f);
        if (gr < M) va = *(const float4*)(Arow + k0 + lc);
        if (gn < N) vb = *(const float4*)(Brow + k0 + lc);
        As[lc + 0][lr] = va.x; As[lc + 1][lr] = va.y;
        As[lc + 2][lr] = va.z; As[lc + 3][lr] = va.w;
        Bs[lc + 0][lr] = vb.x; Bs[lc + 1][lr] = vb.y;
        Bs[lc + 2][lr] = vb.z; Bs[lc + 3][lr] = vb.w;
        __syncthreads();
#pragma unroll
        for (int k = 0; k < BK; ++k) {
            float4 a4 = *(const float4*)(&As[k][ty << 2]);
            float4 b4 = *(const float4*)(&Bs[k][tx << 2]);
            float a[4] = {a4.x, a4.y, a4.z, a4.w};
            float b[4] = {b4.x, b4.y, b4.z, b4.w};
#pragma unroll
            for (int i = 0; i < 4; ++i)
#pragma unroll
                for (int j = 0; j < 4; ++j)
                    acc[i][j] = fmaf(a[i], b[j], acc[i][j]);
        }
        __syncthreads();
    }
#pragma unroll
    for (int i = 0; i < 4; ++i) {
        int m = bm + (ty << 2) + i;
        if (m >= M) continue;
#pragma unroll
        for (int j = 0; j < 4; ++j) {
            int n = bn + (tx << 2) + j;
            if (n < N) store_c(&Cc[(size_t)m * ldc + n], acc[i][j] + (bias ? bias[n] : 0.f));
        }
    }
}

__global__ __launch_bounds__(256)
void prep_wcat(const float* __restrict__ W_h2h, const float* __restrict__ W_hh,
               const float* __restrict__ b_h2h, const float* __restrict__ b_hh,
               float* __restrict__ Wcat, float* __restrict__ bcat,
               float* __restrict__ hidden) {
    int idx = blockIdx.x * 256 + threadIdx.x;
    int r = idx >> 8, c = idx & 255;
    Wcat[idx] = (r < 256) ? W_h2h[r * 256 + c] : W_hh[(r - 256) * 256 + c];
    if (idx < 1024) bcat[idx] = (idx < 256) ? b_h2h[idx] : b_hh[idx - 256];
    if (idx < BATCH * HID) hidden[idx] = 0.f;
}

template <typename HT>
__global__ __launch_bounds__(256)
void attn_step(const HT* __restrict__ Hproj,
               const float* __restrict__ batchH,
               const float* __restrict__ hg,
               const float* __restrict__ Wscore,
               float* __restrict__ context) {
    const int b = blockIdx.x;
    const int tid = threadIdx.x;
    __shared__ float hp[HID];
    __shared__ float wsc[HID];
    __shared__ float es[TLEN];
    __shared__ float red[16];
    hp[tid] = hg[b * 1024 + tid];
    wsc[tid] = Wscore[tid];
    __syncthreads();
    const int wave = tid >> 6;
    const int lane = tid & 63;
    const HT* Hp = Hproj + (size_t)b * TLEN * HID;
    for (int t = wave; t < TLEN; t += 4) {
        float x0, x1, x2, x3;
        if constexpr (sizeof(HT) == 4) {
            float4 hv = *(const float4*)((const float*)Hp + (size_t)t * HID + (lane << 2));
            x0 = hv.x; x1 = hv.y; x2 = hv.z; x3 = hv.w;
        } else {
            ushort4 hv = *(const ushort4*)((const ushort_t*)Hp + (size_t)t * HID + (lane << 2));
            x0 = bf2f(hv.x); x1 = bf2f(hv.y); x2 = bf2f(hv.z); x3 = bf2f(hv.w);
        }
        float4 hpv = *(const float4*)(&hp[lane << 2]);
        float4 wv = *(const float4*)(&wsc[lane << 2]);
        float sc = fast_tanh(x0 + hpv.x) * wv.x
                 + fast_tanh(x1 + hpv.y) * wv.y
                 + fast_tanh(x2 + hpv.z) * wv.z
                 + fast_tanh(x3 + hpv.w) * wv.w;
#pragma unroll
        for (int off = 32; off >= 1; off >>= 1) sc += __shfl_xor(sc, off);
        if (lane == 0) es[t] = sc;
    }
    __syncthreads();
    float e = (tid < TLEN) ? es[tid] : -INFINITY;
    float m = e;
#pragma unroll
    for (int off = 32; off >= 1; off >>= 1) m = fmaxf(m, __shfl_xor(m, off));
    if (lane == 0) red[wave] = m;
    __syncthreads();
    m = fmaxf(fmaxf(red[0], red[1]), fmaxf(red[2], red[3]));
    float p = (tid < TLEN) ? __expf(e - m) : 0.f;
    float ss = p;
#pragma unroll
    for (int off = 32; off >= 1; off >>= 1) ss += __shfl_xor(ss, off);
    if (lane == 0) red[8 + wave] = ss;
    __syncthreads();
    float denom = red[8] + red[9] + red[10] + red[11];
    if (tid < TLEN) es[tid] = p / denom;
    __syncthreads();
    const float* Hb = batchH + (size_t)b * TLEN * DIN;
    float acc0 = 0.f, acc1 = 0.f;
#pragma unroll 4
    for (int t = 0; t < TLEN; ++t) {
        float a = es[t];
        acc0 = fmaf(a, Hb[(size_t)t * DIN + tid], acc0);
        acc1 = fmaf(a, Hb[(size_t)t * DIN + HID + tid], acc1);
    }
    context[(size_t)b * DIN + tid] = acc0;
    context[(size_t)b * DIN + HID + tid] = acc1;
}

__global__ __launch_bounds__(256)
void gru_gate_gen(const float* __restrict__ gi,
                  const float* __restrict__ hg,
                  float* __restrict__ hidden,
                  float* __restrict__ out,
                  const int* __restrict__ text,
                  int s,
                  const float* __restrict__ W_ih,
                  const float* __restrict__ W_gen,
                  const float* __restrict__ b_gen) {
    const int b = blockIdx.x;
    const int h = threadIdx.x;
    __shared__ float sh[HID];
    const int ch = text[b * STEPS + s];
    const float* gib = gi + (size_t)b * G3;
    const float* ghb = hg + (size_t)b * 1024 + 256;
    float ir = gib[h]        + W_ih[(size_t)h * GRUIN + DIN + ch];
    float iz = gib[256 + h]  + W_ih[(size_t)(256 + h) * GRUIN + DIN + ch];
    float in_ = gib[512 + h] + W_ih[(size_t)(512 + h) * GRUIN + DIN + ch];
    float hr = ghb[h];
    float hz = ghb[256 + h];
    float hn = ghb[512 + h];
    float r = fast_sigmoid(ir + hr);
    float z = fast_sigmoid(iz + hz);
    float n = fast_tanh(in_ + r * hn);
    float hprev = hidden[b * HID + h];
    float nh = (1.f - z) * n + z * hprev;
    hidden[b * HID + h] = nh;
    sh[h] = nh;
    __syncthreads();
    if (h < NCLS) {
        const float* wg = W_gen + (size_t)h * HID;
        float acc = b_gen[h];
#pragma unroll 4
        for (int k = 0; k < HID; k += 4) {
            float4 w4 = *(const float4*)(wg + k);
            acc = fmaf(sh[k], w4.x, acc);
            acc = fmaf(sh[k + 1], w4.y, acc);
            acc = fmaf(sh[k + 2], w4.z, acc);
            acc = fmaf(sh[k + 3], w4.w, acc);
        }
        out[((size_t)b * STEPS + s) * NCLS + h] = acc;
    }
}

extern "C" void kernel_launch(void* const* d_in, const int* in_sizes, int n_in,
                              void* d_out, int out_size, void* d_ws, size_t ws_size,
                              hipStream_t stream) {
    const float* batch_H = (const float*)d_in[0];
    const int* text      = (const int*)d_in[1];
    const float* W_i2h   = (const float*)d_in[3];
    const float* W_h2h   = (const float*)d_in[4];
    const float* b_h2h   = (const float*)d_in[5];
    const float* W_score = (const float*)d_in[6];
    const float* W_ih    = (const float*)d_in[7];
    const float* W_hh    = (const float*)d_in[8];
    const float* b_ih    = (const float*)d_in[9];
    const float* b_hh    = (const float*)d_in[10];
    const float* W_gen   = (const float*)d_in[11];
    const float* b_gen   = (const float*)d_in[12];
    float* out = (float*)d_out;
    char* ws = (char*)d_ws;

    const size_t M = (size_t)BATCH * TLEN;              // 65536
    const size_t nBH = M * DIN;
    // workspace layout (bytes)
    const size_t a16_off  = 0;                          // 67,108,864
    const size_t hpB_off  = 67108864;                   // 33,554,432
    const size_t wih_off  = hpB_off + 33554432;         // 786,432
    const size_t wi2h_off = wih_off + 786432;           // 262,144
    const size_t wcat_off = wi2h_off + 262144;          // 524,288
    const size_t wemb_off = wcat_off + 524288;          // 294,912
    const size_t wgen_off = wemb_off + 294912;          // 49,152
    const size_t bcat_off = wgen_off + 49152;           // 4,096
    const size_t hg_off   = bcat_off + 4096;            // 2,097,152
    const size_t hid_off  = hg_off + 2097152;           // 524,288
    const size_t ctx_off  = hid_off + 524288;           // 524,288
    const size_t gi_off   = ctx_off + 524288;           // 1,572,864
    const size_t need_new = gi_off + 1572864;           // ~107.3 MB

    if (ws_size >= need_new) {
        ushort_t* A16    = (ushort_t*)(ws + a16_off);
        ushort_t* Hp16   = (ushort_t*)(ws + hpB_off);
        ushort_t* Wih16  = (ushort_t*)(ws + wih_off);
        ushort_t* Wi2h16 = (ushort_t*)(ws + wi2h_off);
        ushort_t* Wcat16 = (ushort_t*)(ws + wcat_off);
        float*    WembT  = (float*)(ws + wemb_off);
        ushort_t* Wgen16 = (ushort_t*)(ws + wgen_off);
        float*    bcat   = (float*)(ws + bcat_off);
        float*    hg     = (float*)(ws + hg_off);
        float*    hidden = (float*)(ws + hid_off);
        ushort_t* ctx16  = (ushort_t*)(ws + ctx_off);
        float*    gi_g   = (float*)(ws + gi_off);

        hipLaunchKernelGGL(prep_all, dim3(6020), dim3(256), 0, stream,
                           W_h2h, W_hh, W_ih, W_i2h, b_ih, b_h2h, b_hh, W_gen,
                           Wih16, Wi2h16, Wcat16, WembT, Wgen16, bcat, hidden, hg);
        hipLaunchKernelGGL(conv_a16, dim3(2048), dim3(256), 0, stream,
                           batch_H, A16, (int)(nBH / 8));
        hipLaunchKernelGGL(hp_mfma, dim3(1024), dim3(256), 0, stream,
                           A16, Wi2h16, Hp16);
        for (int s = 0; s < STEPS; ++s) {
            hipLaunchKernelGGL(step_attn, dim3(BATCH), dim3(1024), 0, stream,
                               Hp16, A16, hg, W_score, ctx16);
            hipLaunchKernelGGL(gigru_hg, dim3(16), dim3(512), 0, stream,
                               ctx16, Wih16, Wcat16, Wgen16, WembT, bcat, b_gen,
                               text, s, gi_g, hg, hidden, out);
        }
        return;
    }

    // ---------------- fallback: round-3 Plan B ----------------
    const size_t nHp = M * HID;
    const size_t small_floats = (size_t)BATCH * HID + BATCH * 1024 + BATCH * DIN
                              + BATCH * G3 + 1024 * HID + 1024;
    const size_t need_B32 = nHp * 4 + small_floats * 4;
    const bool use_fp32 = (ws_size >= need_B32);
    const size_t hp_bytes = use_fp32 ? nHp * 4 : nHp * 2;
    void* Hproj = (void*)ws;
    float* hiddenB = (float*)(ws + hp_bytes);
    float* hgB     = hiddenB + BATCH * HID;
    float* context = hgB + BATCH * 1024;
    float* gi      = context + BATCH * DIN;
    float* Wcat    = gi + BATCH * G3;
    float* bcatB   = Wcat + 1024 * HID;

    hipLaunchKernelGGL(prep_wcat, dim3(1024), dim3(256), 0, stream,
                       W_h2h, W_hh, b_h2h, b_hh, Wcat, bcatB, hiddenB);
    if (use_fp32) {
        hipLaunchKernelGGL(gemm_nt<float>, dim3(M / BM, HID / BN), dim3(256), 0, stream,
                           batch_H, DIN, W_i2h, DIN, (float*)Hproj, HID, (const float*)nullptr,
                           (int)M, HID, DIN);
    } else {
        hipLaunchKernelGGL(gemm_nt<ushort_t>, dim3(M / BM, HID / BN), dim3(256), 0, stream,
                           batch_H, DIN, W_i2h, DIN, (ushort_t*)Hproj, HID, (const float*)nullptr,
                           (int)M, HID, DIN);
    }
    for (int s = 0; s < STEPS; ++s) {
        hipLaunchKernelGGL(gemm_nt<float>, dim3(BATCH / BM, 1024 / BN), dim3(256), 0, stream,
                           hiddenB, HID, Wcat, HID, hgB, 1024, bcatB, BATCH, 1024, HID);
        if (use_fp32) {
            hipLaunchKernelGGL(attn_step<float>, dim3(BATCH), dim3(256), 0, stream,
                               (const float*)Hproj, batch_H, hgB, W_score, context);
        } else {
            hipLaunchKernelGGL(attn_step<ushort_t>, dim3(BATCH), dim3(256), 0, stream,
                               (const ushort_t*)Hproj, batch_H, hgB, W_score, context);
        }
        hipLaunchKernelGGL(gemm_nt<float>, dim3(BATCH / BM, G3 / BN), dim3(256), 0, stream,
                           context, DIN, W_ih, GRUIN, gi, G3, b_ih, BATCH, G3, DIN);
        hipLaunchKernelGGL(gru_gate_gen, dim3(BATCH), dim3(HID), 0, stream,
                           gi, hgB, hiddenB, out, text, s, W_ih, W_gen, b_gen);
    }
}

// Round 13
// 1210.808 us; speedup vs baseline: 1.6144x; 1.6144x over previous
//
#include <hip/hip_runtime.h>

#define BATCH 512
#define TLEN 128
#define DIN 512
#define HID 256
#define NCLS 96
#define STEPS 26
#define GRUIN 608
#define G3 768

#define BM 64
#define BN 64
#define BK 16
#define LDS_STRIDE 68

typedef unsigned short ushort_t;
typedef __attribute__((ext_vector_type(8))) short short8v;
typedef __attribute__((ext_vector_type(4))) float f32x4;
typedef __attribute__((ext_vector_type(8))) unsigned short ushort8v;

__device__ __forceinline__ float fast_tanh(float x) {
    return 1.f - 2.f / (__expf(2.f * x) + 1.f);
}
__device__ __forceinline__ float fast_sigmoid(float x) {
    return 1.f / (1.f + __expf(-x));
}
__device__ __forceinline__ ushort_t f2bf_rne(float f) {
    unsigned int u = __float_as_uint(f);
    unsigned int r = (u + 0x7FFFu + ((u >> 16) & 1u)) >> 16;
    return (ushort_t)r;
}
__device__ __forceinline__ float bf2f(ushort_t h) {
    return __uint_as_float(((unsigned int)h) << 16);
}

// ================= one-time prep (round-11, validated) =================
__global__ __launch_bounds__(256)
void prep_all(const float* __restrict__ W_h2h, const float* __restrict__ W_hh,
              const float* __restrict__ W_ih, const float* __restrict__ W_i2h,
              const float* __restrict__ b_ih, const float* __restrict__ b_h2h,
              const float* __restrict__ b_hh, const float* __restrict__ W_gen,
              ushort_t* __restrict__ Wcat16, ushort_t* __restrict__ B16cat,
              float* __restrict__ WembT, ushort_t* __restrict__ Wgen16,
              float* __restrict__ bcat, float* __restrict__ hidden,
              float* __restrict__ hg) {
    int idx = blockIdx.x * 256 + threadIdx.x;
    if (idx < 262144) {
        int n = idx >> 8, k = idx & 255;
        float v = (n < 256) ? W_h2h[n * 256 + k] : W_hh[(size_t)(n - 256) * 256 + k];
        Wcat16[idx] = f2bf_rne(v);
    } else if (idx < 262144 + 524288) {
        int j = idx - 262144;
        int r = j >> 9, c = j & 511;
        float v = (r < 768) ? W_ih[(size_t)r * GRUIN + c] : W_i2h[(size_t)(r - 768) * 512 + c];
        B16cat[j] = f2bf_rne(v);
    } else if (idx < 262144 + 524288 + 73728) {
        int j = idx - (262144 + 524288);
        int ch = j / 768, jj = j - ch * 768;
        WembT[j] = W_ih[(size_t)jj * GRUIN + 512 + ch] + b_ih[jj];
    } else if (idx < 262144 + 524288 + 73728 + 24576) {
        int j = idx - (262144 + 524288 + 73728);
        Wgen16[j] = f2bf_rne(W_gen[j]);
    } else if (idx < 262144 + 524288 + 73728 + 24576 + 1024) {
        int j = idx - (262144 + 524288 + 73728 + 24576);
        bcat[j] = (j < 256) ? b_h2h[j] : b_hh[j - 256];
    } else if (idx < 262144 + 524288 + 73728 + 24576 + 1024 + 131072) {
        int j = idx - (262144 + 524288 + 73728 + 24576 + 1024);
        hidden[j] = 0.f;
    } else if (idx < 262144 + 524288 + 73728 + 24576 + 1024 + 131072 + 524288) {
        int j = idx - (262144 + 524288 + 73728 + 24576 + 1024 + 131072);
        int c = j & 1023;
        hg[j] = (c < 256) ? b_h2h[c] : b_hh[c - 256];   // hg for s=0 (hidden=0)
    }
}

// ================= batch_H fp32 -> bf16 =================
__global__ __launch_bounds__(256)
void conv_a16(const float* __restrict__ src, ushort_t* __restrict__ dst, int n8) {
    int i = blockIdx.x * 256 + threadIdx.x;
    const int stride = gridDim.x * 256;
    for (; i < n8; i += stride) {
        float4 v0 = ((const float4*)src)[2 * i];
        float4 v1 = ((const float4*)src)[2 * i + 1];
        ushort8v o;
        o[0] = f2bf_rne(v0.x); o[1] = f2bf_rne(v0.y);
        o[2] = f2bf_rne(v0.z); o[3] = f2bf_rne(v0.w);
        o[4] = f2bf_rne(v1.x); o[5] = f2bf_rne(v1.y);
        o[6] = f2bf_rne(v1.z); o[7] = f2bf_rne(v1.w);
        ((ushort8v*)dst)[i] = o;
    }
}

// LDS swizzle (validated): dense 32-ushort rows, XOR quad index
__device__ __forceinline__ int swz(int row, int col8) {
    return (row * 32 + col8 * 8) ^ ((row & 7) << 3);
}

// ================= MFMA GEMM -> split outputs HW16[M][768], Hp16[M][256] =================
// Round-13 change: coalesced C writes via 32KB LDS staging (was 64 scalar 2B stores/thread).
__global__ __launch_bounds__(256)
void hwhp_mfma(const ushort_t* __restrict__ A16,
               const ushort_t* __restrict__ B16,
               ushort_t* __restrict__ HW16,
               ushort_t* __restrict__ Hp16) {
    __shared__ ushort_t As[128 * 32];
    __shared__ ushort_t Bs[128 * 32];
    __shared__ ushort_t Cs[128 * 128];   // 32 KB staging for coalesced writes
    const int wgid = blockIdx.x;
    const int mt = (wgid & 7) + ((wgid >> 6) << 3);
    const int nt = (wgid >> 3) & 7;
    const int bm = mt * 128, bn = nt * 128;
    const int tid = threadIdx.x;
    const int wid = tid >> 6, lane = tid & 63;
    const int wr = wid >> 1, wc = wid & 1;
    const int sr = tid >> 2, sq = tid & 3;
    f32x4 acc[4][4] = {};
    const int l15 = lane & 15, lhi = lane >> 4;
    for (int k0 = 0; k0 < 512; k0 += 32) {
        ushort8v a0 = *(const ushort8v*)(A16 + (size_t)(bm + sr) * 512 + k0 + sq * 8);
        ushort8v a1 = *(const ushort8v*)(A16 + (size_t)(bm + sr + 64) * 512 + k0 + sq * 8);
        ushort8v b0 = *(const ushort8v*)(B16 + (size_t)(bn + sr) * 512 + k0 + sq * 8);
        ushort8v b1 = *(const ushort8v*)(B16 + (size_t)(bn + sr + 64) * 512 + k0 + sq * 8);
        __syncthreads();
        *(ushort8v*)(&As[swz(sr, sq)]) = a0;
        *(ushort8v*)(&As[swz(sr + 64, sq)]) = a1;
        *(ushort8v*)(&Bs[swz(sr, sq)]) = b0;
        *(ushort8v*)(&Bs[swz(sr + 64, sq)]) = b1;
        __syncthreads();
        short8v af[4], bfr[4];
#pragma unroll
        for (int i = 0; i < 4; ++i) {
            int arow = wr * 64 + i * 16 + l15;
            af[i] = *(const short8v*)(&As[swz(arow, lhi)]);
            int brow = wc * 64 + i * 16 + l15;
            bfr[i] = *(const short8v*)(&Bs[swz(brow, lhi)]);
        }
#pragma unroll
        for (int i = 0; i < 4; ++i)
#pragma unroll
            for (int j = 0; j < 4; ++j)
                acc[i][j] = __builtin_amdgcn_mfma_f32_16x16x32_bf16(af[i], bfr[j], acc[i][j], 0, 0, 0);
    }
    // stage C tile in LDS (row-major [128][128])
#pragma unroll
    for (int i = 0; i < 4; ++i)
#pragma unroll
        for (int j = 0; j < 4; ++j)
#pragma unroll
            for (int p = 0; p < 4; ++p)
                Cs[(wr * 64 + i * 16 + lhi * 4 + p) * 128 + wc * 64 + j * 16 + l15] =
                    f2bf_rne(acc[i][j][p]);
    __syncthreads();
    // coalesced copy out: 256 thr x 16B x 8 iters
    const bool isHW = (bn < 768);
    ushort_t* outp = isHW ? HW16 : Hp16;
    const int ld = isHW ? 768 : 256;
    const int cbase = isHW ? bn : (bn - 768);
#pragma unroll
    for (int it = 0; it < 8; ++it) {
        int off = it * 2048 + tid * 8;           // ushort offset in Cs
        int row = off >> 7, col = off & 127;
        ushort8v v = *(const ushort8v*)(&Cs[off]);
        *(ushort8v*)(outp + (size_t)(bm + row) * ld + cbase + col) = v;
    }
}

// ================= per-step hg GEMM: hg[512,1024] = hidden16 @ Wcat16^T + bcat =================
__global__ __launch_bounds__(256)
void hg_mfma(const ushort_t* __restrict__ H16,    // [512][256] bf16
             const ushort_t* __restrict__ W16,    // [1024][256] bf16
             const float* __restrict__ bcat,      // [1024]
             float* __restrict__ hg) {            // [512][1024]
    __shared__ ushort_t As[128 * 32];
    __shared__ ushort_t Bs[128 * 32];
    const int wgid = blockIdx.x;                  // 32 blocks: 4 mt x 8 nt
    const int mt = wgid >> 3;
    const int nt = wgid & 7;
    const int bm = mt * 128, bn = nt * 128;
    const int tid = threadIdx.x;
    const int wid = tid >> 6, lane = tid & 63;
    const int wr = wid >> 1, wc = wid & 1;
    const int sr = tid >> 2, sq = tid & 3;
    f32x4 acc[4][4] = {};
    const int l15 = lane & 15, lhi = lane >> 4;
    for (int k0 = 0; k0 < 256; k0 += 32) {
        ushort8v a0 = *(const ushort8v*)(H16 + (size_t)(bm + sr) * 256 + k0 + sq * 8);
        ushort8v a1 = *(const ushort8v*)(H16 + (size_t)(bm + sr + 64) * 256 + k0 + sq * 8);
        ushort8v b0 = *(const ushort8v*)(W16 + (size_t)(bn + sr) * 256 + k0 + sq * 8);
        ushort8v b1 = *(const ushort8v*)(W16 + (size_t)(bn + sr + 64) * 256 + k0 + sq * 8);
        __syncthreads();
        *(ushort8v*)(&As[swz(sr, sq)]) = a0;
        *(ushort8v*)(&As[swz(sr + 64, sq)]) = a1;
        *(ushort8v*)(&Bs[swz(sr, sq)]) = b0;
        *(ushort8v*)(&Bs[swz(sr + 64, sq)]) = b1;
        __syncthreads();
        short8v af[4], bfr[4];
#pragma unroll
        for (int i = 0; i < 4; ++i) {
            int arow = wr * 64 + i * 16 + l15;
            af[i] = *(const short8v*)(&As[swz(arow, lhi)]);
            int brow = wc * 64 + i * 16 + l15;
            bfr[i] = *(const short8v*)(&Bs[swz(brow, lhi)]);
        }
#pragma unroll
        for (int i = 0; i < 4; ++i)
#pragma unroll
            for (int j = 0; j < 4; ++j)
                acc[i][j] = __builtin_amdgcn_mfma_f32_16x16x32_bf16(af[i], bfr[j], acc[i][j], 0, 0, 0);
    }
    const int cr0 = bm + wr * 64 + lhi * 4;
    const int cc0 = bn + wc * 64 + l15;
#pragma unroll
    for (int j = 0; j < 4; ++j) {
        const int c = cc0 + j * 16;
        const float bj = bcat[c];
#pragma unroll
        for (int i = 0; i < 4; ++i)
#pragma unroll
            for (int p = 0; p < 4; ++p)
                hg[(size_t)(cr0 + i * 16 + p) * 1024 + c] = acc[i][j][p] + bj;
    }
}

// ================= per-step fused: scores+softmax+gi+GRU+generator (round-11, validated) =================
__global__ __launch_bounds__(1024)
void step_fused(const ushort_t* __restrict__ HW16,    // [M][768] bf16
                const ushort_t* __restrict__ Hp16,    // [M][256] bf16
                const float* __restrict__ hg,         // [B][1024] fp32 (h_proj | gh)
                const float* __restrict__ WembT,      // [96][768]
                const ushort_t* __restrict__ Wgen16,  // [96][256]
                const float* __restrict__ Wscore,
                const float* __restrict__ b_gen,
                const int* __restrict__ text,
                int s,
                float* __restrict__ hidden,           // [B][256] fp32 in/out
                ushort_t* __restrict__ hidden16,      // [B][256] bf16 out
                float* __restrict__ out) {
    const int b = blockIdx.x;
    const int tid = threadIdx.x;   // 1024
    const int wave = tid >> 6, lane = tid & 63;

    __shared__ __align__(16) float hp[HID];
    __shared__ __align__(16) float wsc[HID];
    __shared__ __align__(16) float parts[6144];   // 24 KB (pass3: 8x768)
    __shared__ __align__(16) float gi_l[G3];
    __shared__ __align__(16) float sh[HID];
    __shared__ float es[TLEN];
    __shared__ float al[TLEN];
    __shared__ float red[16];

    const size_t rowbase = (size_t)b * TLEN;
    if (tid < 256) {
        hp[tid] = hg[(size_t)b * 1024 + tid];
        wsc[tid] = Wscore[tid];
    }
    __syncthreads();

    // ---- pass 1: scores; full wave per t; Hp rows 512B contiguous
#pragma unroll
    for (int i = 0; i < 8; ++i) {
        int t = i * 16 + wave;
        ushort4 hv = *(const ushort4*)(Hp16 + (rowbase + t) * 256 + lane * 4);
        float4 hpv = *(const float4*)(&hp[lane * 4]);
        float4 wv = *(const float4*)(&wsc[lane * 4]);
        float sc = fast_tanh(bf2f(hv.x) + hpv.x) * wv.x
                 + fast_tanh(bf2f(hv.y) + hpv.y) * wv.y
                 + fast_tanh(bf2f(hv.z) + hpv.z) * wv.z
                 + fast_tanh(bf2f(hv.w) + hpv.w) * wv.w;
#pragma unroll
        for (int off = 32; off >= 1; off >>= 1) sc += __shfl_xor(sc, off);
        if (lane == 0) es[t] = sc;
    }
    __syncthreads();
    // ---- pass 2: softmax (threads 0..127)
    float ev = 0.f, p = 0.f;
    if (tid < TLEN) {
        ev = es[tid];
        float mx = ev;
#pragma unroll
        for (int off = 32; off >= 1; off >>= 1) mx = fmaxf(mx, __shfl_xor(mx, off));
        if (lane == 0) red[wave] = mx;
    }
    __syncthreads();
    if (tid < TLEN) {
        float m = fmaxf(red[0], red[1]);
        p = __expf(ev - m);
        float sm = p;
#pragma unroll
        for (int off = 32; off >= 1; off >>= 1) sm += __shfl_xor(sm, off);
        if (lane == 0) red[8 + wave] = sm;
    }
    __syncthreads();
    if (tid < TLEN) al[tid] = p / (red[8] + red[9]);
    __syncthreads();
    // ---- pass 3: gi partials; 8 t-groups x 96 col-quads on HW rows
    {
        const int tg = tid >> 7;
        const int cq = tid & 127;
        if (cq < 96) {
            float a0 = 0.f, a1 = 0.f, a2 = 0.f, a3 = 0.f;
            float a4 = 0.f, a5 = 0.f, a6 = 0.f, a7 = 0.f;
            const ushort_t* base = HW16 + (rowbase + tg * 16) * 768 + cq * 8;
            const float* alh = &al[tg * 16];
#pragma unroll 8
            for (int i = 0; i < 16; ++i) {
                ushort8v v = *(const ushort8v*)(base + (size_t)i * 768);
                float a = alh[i];
                a0 = fmaf(a, bf2f(v[0]), a0);
                a1 = fmaf(a, bf2f(v[1]), a1);
                a2 = fmaf(a, bf2f(v[2]), a2);
                a3 = fmaf(a, bf2f(v[3]), a3);
                a4 = fmaf(a, bf2f(v[4]), a4);
                a5 = fmaf(a, bf2f(v[5]), a5);
                a6 = fmaf(a, bf2f(v[6]), a6);
                a7 = fmaf(a, bf2f(v[7]), a7);
            }
            float* pr = &parts[tg * 768 + cq * 8];
            pr[0] = a0; pr[1] = a1; pr[2] = a2; pr[3] = a3;
            pr[4] = a4; pr[5] = a5; pr[6] = a6; pr[7] = a7;
        }
    }
    __syncthreads();
    if (tid < G3) {
        float g = parts[tid] + parts[768 + tid] + parts[1536 + tid] + parts[2304 + tid]
                + parts[3072 + tid] + parts[3840 + tid] + parts[4608 + tid] + parts[5376 + tid];
        gi_l[tid] = g;
    }
    __syncthreads();
    // ---- pass 4: GRU gates (threads 0..255) -> sh, hidden, hidden16
    if (tid < 256) {
        const int ch = text[b * STEPS + s];
        const float* em = WembT + (size_t)ch * G3;
        const float* ghb = hg + (size_t)b * 1024 + 256;
        float ir = gi_l[tid]       + em[tid]       + ghb[tid];
        float iz = gi_l[256 + tid] + em[256 + tid] + ghb[256 + tid];
        float in_ = gi_l[512 + tid] + em[512 + tid];
        float hn = ghb[512 + tid];
        float rr = fast_sigmoid(ir);
        float zz = fast_sigmoid(iz);
        float nn = fast_tanh(in_ + rr * hn);
        float nh = (1.f - zz) * nn + zz * hidden[(size_t)b * HID + tid];
        hidden[(size_t)b * HID + tid] = nh;
        hidden16[(size_t)b * HID + tid] = f2bf_rne(nh);
        sh[tid] = nh;
    }
    __syncthreads();
    // ---- pass 5: generator (threads 0..95)
    if (tid < NCLS) {
        const ushort_t* wrow = Wgen16 + (size_t)tid * HID;
        float acc = b_gen[tid];
#pragma unroll 4
        for (int k = 0; k < HID; k += 8) {
            ushort8v w8 = *(const ushort8v*)(wrow + k);
            acc = fmaf(sh[k],     bf2f(w8[0]), acc);
            acc = fmaf(sh[k + 1], bf2f(w8[1]), acc);
            acc = fmaf(sh[k + 2], bf2f(w8[2]), acc);
            acc = fmaf(sh[k + 3], bf2f(w8[3]), acc);
            acc = fmaf(sh[k + 4], bf2f(w8[4]), acc);
            acc = fmaf(sh[k + 5], bf2f(w8[5]), acc);
            acc = fmaf(sh[k + 6], bf2f(w8[6]), acc);
            acc = fmaf(sh[k + 7], bf2f(w8[7]), acc);
        }
        out[((size_t)b * STEPS + s) * NCLS + tid] = acc;
    }
}

// ================= generic fp32 GEMM (fallback) =================
template <typename OutT>
__device__ __forceinline__ void store_c(OutT* p, float v);
template <> __device__ __forceinline__ void store_c<float>(float* p, float v) { *p = v; }
template <> __device__ __forceinline__ void store_c<ushort_t>(ushort_t* p, float v) { *p = f2bf_rne(v); }

template <typename OutT>
__global__ __launch_bounds__(256)
void gemm_nt(const float* __restrict__ A, int lda,
             const float* __restrict__ Bw, int ldb,
             OutT* __restrict__ Cc, int ldc,
             const float* __restrict__ bias,
             int M, int N, int K) {
    __shared__ float As[BK][LDS_STRIDE];
    __shared__ float Bs[BK][LDS_STRIDE];
    const int tid = threadIdx.x;
    const int bm = blockIdx.x * BM;
    const int bn = blockIdx.y * BN;
    const int tx = tid & 15, ty = tid >> 4;
    const int lr = tid >> 2;
    const int lc = (tid & 3) << 2;
    float acc[4][4] = {};
    const int gr = bm + lr;
    const int gn = bn + lr;
    const float* Arow = A + (size_t)gr * lda;
    const float* Brow = Bw + (size_t)gn * ldb;
    for (int k0 = 0; k0 < K; k0 += BK) {
        float4 va = make_float4(0.f, 0.f, 0.f, 0.f);
        float4 vb = make_float4(0.f, 0.f, 0.f, 0.f);
        if (gr < M) va = *(const float4*)(Arow + k0 + lc);
        if (gn < N) vb = *(const float4*)(Brow + k0 + lc);
        As[lc + 0][lr] = va.x; As[lc + 1][lr] = va.y;
        As[lc + 2][lr] = va.z; As[lc + 3][lr] = va.w;
        Bs[lc + 0][lr] = vb.x; Bs[lc + 1][lr] = vb.y;
        Bs[lc + 2][lr] = vb.z; Bs[lc + 3][lr] = vb.w;
        __syncthreads();
#pragma unroll
        for (int k = 0; k < BK; ++k) {
            float4 a4 = *(const float4*)(&As[k][ty << 2]);
            float4 b4 = *(const float4*)(&Bs[k][tx << 2]);
            float a[4] = {a4.x, a4.y, a4.z, a4.w};
            float b[4] = {b4.x, b4.y, b4.z, b4.w};
#pragma unroll
            for (int i = 0; i < 4; ++i)
#pragma unroll
                for (int j = 0; j < 4; ++j)
                    acc[i][j] = fmaf(a[i], b[j], acc[i][j]);
        }
        __syncthreads();
    }
#pragma unroll
    for (int i = 0; i < 4; ++i) {
        int m = bm + (ty << 2) + i;
        if (m >= M) continue;
#pragma unroll
        for (int j = 0; j < 4; ++j) {
            int n = bn + (tx << 2) + j;
            if (n < N) store_c(&Cc[(size_t)m * ldc + n], acc[i][j] + (bias ? bias[n] : 0.f));
        }
    }
}

// ================= fallback kernels (round-3 Plan B, validated) =================
__global__ __launch_bounds__(256)
void prep_wcat(const float* __restrict__ W_h2h, const float* __restrict__ W_hh,
               const float* __restrict__ b_h2h, const float* __restrict__ b_hh,
               float* __restrict__ Wcat, float* __restrict__ bcat,
               float* __restrict__ hidden) {
    int idx = blockIdx.x * 256 + threadIdx.x;
    int r = idx >> 8, c = idx & 255;
    Wcat[idx] = (r < 256) ? W_h2h[r * 256 + c] : W_hh[(r - 256) * 256 + c];
    if (idx < 1024) bcat[idx] = (idx < 256) ? b_h2h[idx] : b_hh[idx - 256];
    if (idx < BATCH * HID) hidden[idx] = 0.f;
}

template <typename HT>
__global__ __launch_bounds__(256)
void attn_step(const HT* __restrict__ Hproj,
               const float* __restrict__ batchH,
               const float* __restrict__ hg,
               const float* __restrict__ Wscore,
               float* __restrict__ context) {
    const int b = blockIdx.x;
    const int tid = threadIdx.x;
    __shared__ float hp[HID];
    __shared__ float wsc[HID];
    __shared__ float es[TLEN];
    __shared__ float red[16];
    hp[tid] = hg[b * 1024 + tid];
    wsc[tid] = Wscore[tid];
    __syncthreads();
    const int wave = tid >> 6;
    const int lane = tid & 63;
    const HT* Hp = Hproj + (size_t)b * TLEN * HID;
    for (int t = wave; t < TLEN; t += 4) {
        float x0, x1, x2, x3;
        if constexpr (sizeof(HT) == 4) {
            float4 hv = *(const float4*)((const float*)Hp + (size_t)t * HID + (lane << 2));
            x0 = hv.x; x1 = hv.y; x2 = hv.z; x3 = hv.w;
        } else {
            ushort4 hv = *(const ushort4*)((const ushort_t*)Hp + (size_t)t * HID + (lane << 2));
            x0 = bf2f(hv.x); x1 = bf2f(hv.y); x2 = bf2f(hv.z); x3 = bf2f(hv.w);
        }
        float4 hpv = *(const float4*)(&hp[lane << 2]);
        float4 wv = *(const float4*)(&wsc[lane << 2]);
        float sc = fast_tanh(x0 + hpv.x) * wv.x
                 + fast_tanh(x1 + hpv.y) * wv.y
                 + fast_tanh(x2 + hpv.z) * wv.z
                 + fast_tanh(x3 + hpv.w) * wv.w;
#pragma unroll
        for (int off = 32; off >= 1; off >>= 1) sc += __shfl_xor(sc, off);
        if (lane == 0) es[t] = sc;
    }
    __syncthreads();
    float e = (tid < TLEN) ? es[tid] : -INFINITY;
    float m = e;
#pragma unroll
    for (int off = 32; off >= 1; off >>= 1) m = fmaxf(m, __shfl_xor(m, off));
    if (lane == 0) red[wave] = m;
    __syncthreads();
    m = fmaxf(fmaxf(red[0], red[1]), fmaxf(red[2], red[3]));
    float p = (tid < TLEN) ? __expf(e - m) : 0.f;
    float ss = p;
#pragma unroll
    for (int off = 32; off >= 1; off >>= 1) ss += __shfl_xor(ss, off);
    if (lane == 0) red[8 + wave] = ss;
    __syncthreads();
    float denom = red[8] + red[9] + red[10] + red[11];
    if (tid < TLEN) es[tid] = p / denom;
    __syncthreads();
    const float* Hb = batchH + (size_t)b * TLEN * DIN;
    float acc0 = 0.f, acc1 = 0.f;
#pragma unroll 4
    for (int t = 0; t < TLEN; ++t) {
        float a = es[t];
        acc0 = fmaf(a, Hb[(size_t)t * DIN + tid], acc0);
        acc1 = fmaf(a, Hb[(size_t)t * DIN + HID + tid], acc1);
    }
    context[(size_t)b * DIN + tid] = acc0;
    context[(size_t)b * DIN + HID + tid] = acc1;
}

__global__ __launch_bounds__(256)
void gru_gate_gen(const float* __restrict__ gi,
                  const float* __restrict__ hg,
                  float* __restrict__ hidden,
                  float* __restrict__ out,
                  const int* __restrict__ text,
                  int s,
                  const float* __restrict__ W_ih,
                  const float* __restrict__ W_gen,
                  const float* __restrict__ b_gen) {
    const int b = blockIdx.x;
    const int h = threadIdx.x;
    __shared__ float sh[HID];
    const int ch = text[b * STEPS + s];
    const float* gib = gi + (size_t)b * G3;
    const float* ghb = hg + (size_t)b * 1024 + 256;
    float ir = gib[h]        + W_ih[(size_t)h * GRUIN + DIN + ch];
    float iz = gib[256 + h]  + W_ih[(size_t)(256 + h) * GRUIN + DIN + ch];
    float in_ = gib[512 + h] + W_ih[(size_t)(512 + h) * GRUIN + DIN + ch];
    float hr = ghb[h];
    float hz = ghb[256 + h];
    float hn = ghb[512 + h];
    float r = fast_sigmoid(ir + hr);
    float z = fast_sigmoid(iz + hz);
    float n = fast_tanh(in_ + r * hn);
    float hprev = hidden[b * HID + h];
    float nh = (1.f - z) * n + z * hprev;
    hidden[b * HID + h] = nh;
    sh[h] = nh;
    __syncthreads();
    if (h < NCLS) {
        const float* wg = W_gen + (size_t)h * HID;
        float acc = b_gen[h];
#pragma unroll 4
        for (int k = 0; k < HID; k += 4) {
            float4 w4 = *(const float4*)(wg + k);
            acc = fmaf(sh[k], w4.x, acc);
            acc = fmaf(sh[k + 1], w4.y, acc);
            acc = fmaf(sh[k + 2], w4.z, acc);
            acc = fmaf(sh[k + 3], w4.w, acc);
        }
        out[((size_t)b * STEPS + s) * NCLS + h] = acc;
    }
}

extern "C" void kernel_launch(void* const* d_in, const int* in_sizes, int n_in,
                              void* d_out, int out_size, void* d_ws, size_t ws_size,
                              hipStream_t stream) {
    const float* batch_H = (const float*)d_in[0];
    const int* text      = (const int*)d_in[1];
    const float* W_i2h   = (const float*)d_in[3];
    const float* W_h2h   = (const float*)d_in[4];
    const float* b_h2h   = (const float*)d_in[5];
    const float* W_score = (const float*)d_in[6];
    const float* W_ih    = (const float*)d_in[7];
    const float* W_hh    = (const float*)d_in[8];
    const float* b_ih    = (const float*)d_in[9];
    const float* b_hh    = (const float*)d_in[10];
    const float* W_gen   = (const float*)d_in[11];
    const float* b_gen   = (const float*)d_in[12];
    float* out = (float*)d_out;
    char* ws = (char*)d_ws;

    const size_t M = (size_t)BATCH * TLEN;              // 65536
    const size_t nBH = M * DIN;
    // workspace layout (bytes) — identical to round 11
    const size_t hw_off     = 0;                        // HW16:  100,663,296
    const size_t hp_off     = 100663296;                // Hp16:   33,554,432
    const size_t a16_off    = hp_off + 33554432;        // A16:    67,108,864
    const size_t b16cat_off = a16_off + 67108864;       // 1,048,576
    const size_t wcat_off   = b16cat_off + 1048576;     // 524,288
    const size_t wembT_off  = wcat_off + 524288;        // 294,912
    const size_t wgen16_off = wembT_off + 294912;       // 49,152
    const size_t bcat_off   = wgen16_off + 49152;       // 4,096
    const size_t hg_off     = bcat_off + 4096;          // 2,097,152
    const size_t hidden_off = hg_off + 2097152;         // 524,288
    const size_t h16_off    = hidden_off + 524288;      // 262,144
    const size_t need_new   = h16_off + 262144;         // ~206.2 MB

    if (ws_size >= need_new) {
        ushort_t* HW16     = (ushort_t*)(ws + hw_off);
        ushort_t* Hp16     = (ushort_t*)(ws + hp_off);
        ushort_t* A16      = (ushort_t*)(ws + a16_off);
        ushort_t* B16cat   = (ushort_t*)(ws + b16cat_off);
        ushort_t* Wcat16   = (ushort_t*)(ws + wcat_off);
        float*    WembT    = (float*)(ws + wembT_off);
        ushort_t* Wgen16   = (ushort_t*)(ws + wgen16_off);
        float*    bcat     = (float*)(ws + bcat_off);
        float*    hg       = (float*)(ws + hg_off);
        float*    hidden   = (float*)(ws + hidden_off);
        ushort_t* hidden16 = (ushort_t*)(ws + h16_off);

        hipLaunchKernelGGL(prep_all, dim3(6020), dim3(256), 0, stream,
                           W_h2h, W_hh, W_ih, W_i2h, b_ih, b_h2h, b_hh, W_gen,
                           Wcat16, B16cat, WembT, Wgen16, bcat, hidden, hg);
        hipLaunchKernelGGL(conv_a16, dim3(2048), dim3(256), 0, stream,
                           batch_H, A16, (int)(nBH / 8));
        hipLaunchKernelGGL(hwhp_mfma, dim3((M / 128) * 8), dim3(256), 0, stream,
                           A16, B16cat, HW16, Hp16);
        for (int s = 0; s < STEPS; ++s) {
            hipLaunchKernelGGL(step_fused, dim3(BATCH), dim3(1024), 0, stream,
                               HW16, Hp16, hg, WembT, Wgen16, W_score,
                               b_gen, text, s, hidden, hidden16, out);
            if (s < STEPS - 1) {
                hipLaunchKernelGGL(hg_mfma, dim3(32), dim3(256), 0, stream,
                                   hidden16, Wcat16, bcat, hg);
            }
        }
        return;
    }

    // ---------------- fallback: round-3 Plan B ----------------
    const size_t nHp = M * HID;
    const size_t small_floats = (size_t)BATCH * HID + BATCH * 1024 + BATCH * DIN
                              + BATCH * G3 + 1024 * HID + 1024;
    const size_t need_B32 = nHp * 4 + small_floats * 4;
    const bool use_fp32 = (ws_size >= need_B32);
    const size_t hp_bytes = use_fp32 ? nHp * 4 : nHp * 2;
    void* Hproj = (void*)ws;
    float* hiddenB = (float*)(ws + hp_bytes);
    float* hgB     = hiddenB + BATCH * HID;
    float* context = hgB + BATCH * 1024;
    float* gi      = context + BATCH * DIN;
    float* Wcat    = gi + BATCH * G3;
    float* bcatB   = Wcat + 1024 * HID;

    hipLaunchKernelGGL(prep_wcat, dim3(1024), dim3(256), 0, stream,
                       W_h2h, W_hh, b_h2h, b_hh, Wcat, bcatB, hiddenB);
    if (use_fp32) {
        hipLaunchKernelGGL(gemm_nt<float>, dim3(M / BM, HID / BN), dim3(256), 0, stream,
                           batch_H, DIN, W_i2h, DIN, (float*)Hproj, HID, (const float*)nullptr,
                           (int)M, HID, DIN);
    } else {
        hipLaunchKernelGGL(gemm_nt<ushort_t>, dim3(M / BM, HID / BN), dim3(256), 0, stream,
                           batch_H, DIN, W_i2h, DIN, (ushort_t*)Hproj, HID, (const float*)nullptr,
                           (int)M, HID, DIN);
    }
    for (int s = 0; s < STEPS; ++s) {
        hipLaunchKernelGGL(gemm_nt<float>, dim3(BATCH / BM, 1024 / BN), dim3(256), 0, stream,
                           hiddenB, HID, Wcat, HID, hgB, 1024, bcatB, BATCH, 1024, HID);
        if (use_fp32) {
            hipLaunchKernelGGL(attn_step<float>, dim3(BATCH), dim3(256), 0, stream,
                               (const float*)Hproj, batch_H, hgB, W_score, context);
        } else {
            hipLaunchKernelGGL(attn_step<ushort_t>, dim3(BATCH), dim3(256), 0, stream,
                               (const ushort_t*)Hproj, batch_H, hgB, W_score, context);
        }
        hipLaunchKernelGGL(gemm_nt<float>, dim3(BATCH / BM, G3 / BN), dim3(256), 0, stream,
                           context, DIN, W_ih, GRUIN, gi, G3, b_ih, BATCH, G3, DIN);
        hipLaunchKernelGGL(gru_gate_gen, dim3(BATCH), dim3(HID), 0, stream,
                           gi, hgB, hiddenB, out, text, s, W_ih, W_gen, b_gen);
    }
}

// Round 14
// 1071.850 us; speedup vs baseline: 1.8237x; 1.1296x over previous
//
#include <hip/hip_runtime.h>

#define BATCH 512
#define TLEN 128
#define DIN 512
#define HID 256
#define NCLS 96
#define STEPS 26
#define GRUIN 608
#define G3 768

#define BM 64
#define BN 64
#define BK 16
#define LDS_STRIDE 68

typedef unsigned short ushort_t;
typedef __attribute__((ext_vector_type(8))) short short8v;
typedef __attribute__((ext_vector_type(4))) float f32x4;
typedef __attribute__((ext_vector_type(8))) unsigned short ushort8v;

__device__ __forceinline__ float fast_tanh(float x) {
    return 1.f - 2.f / (__expf(2.f * x) + 1.f);
}
__device__ __forceinline__ float fast_sigmoid(float x) {
    return 1.f / (1.f + __expf(-x));
}
__device__ __forceinline__ ushort_t f2bf_rne(float f) {
    unsigned int u = __float_as_uint(f);
    unsigned int r = (u + 0x7FFFu + ((u >> 16) & 1u)) >> 16;
    return (ushort_t)r;
}
__device__ __forceinline__ float bf2f(ushort_t h) {
    return __uint_as_float(((unsigned int)h) << 16);
}

// ================= one-time prep (validated) =================
__global__ __launch_bounds__(256)
void prep_all(const float* __restrict__ W_h2h, const float* __restrict__ W_hh,
              const float* __restrict__ W_ih, const float* __restrict__ W_i2h,
              const float* __restrict__ b_ih, const float* __restrict__ b_h2h,
              const float* __restrict__ b_hh, const float* __restrict__ W_gen,
              ushort_t* __restrict__ Wcat16, ushort_t* __restrict__ B16cat,
              float* __restrict__ WembT, ushort_t* __restrict__ Wgen16,
              float* __restrict__ bcat, float* __restrict__ hidden,
              float* __restrict__ hg) {
    int idx = blockIdx.x * 256 + threadIdx.x;
    if (idx < 262144) {
        int n = idx >> 8, k = idx & 255;
        float v = (n < 256) ? W_h2h[n * 256 + k] : W_hh[(size_t)(n - 256) * 256 + k];
        Wcat16[idx] = f2bf_rne(v);
    } else if (idx < 262144 + 524288) {
        int j = idx - 262144;
        int r = j >> 9, c = j & 511;
        float v = (r < 768) ? W_ih[(size_t)r * GRUIN + c] : W_i2h[(size_t)(r - 768) * 512 + c];
        B16cat[j] = f2bf_rne(v);
    } else if (idx < 262144 + 524288 + 73728) {
        int j = idx - (262144 + 524288);
        int ch = j / 768, jj = j - ch * 768;
        WembT[j] = W_ih[(size_t)jj * GRUIN + 512 + ch] + b_ih[jj];
    } else if (idx < 262144 + 524288 + 73728 + 24576) {
        int j = idx - (262144 + 524288 + 73728);
        Wgen16[j] = f2bf_rne(W_gen[j]);
    } else if (idx < 262144 + 524288 + 73728 + 24576 + 1024) {
        int j = idx - (262144 + 524288 + 73728 + 24576);
        bcat[j] = (j < 256) ? b_h2h[j] : b_hh[j - 256];
    } else if (idx < 262144 + 524288 + 73728 + 24576 + 1024 + 131072) {
        int j = idx - (262144 + 524288 + 73728 + 24576 + 1024);
        hidden[j] = 0.f;
    } else if (idx < 262144 + 524288 + 73728 + 24576 + 1024 + 131072 + 524288) {
        int j = idx - (262144 + 524288 + 73728 + 24576 + 1024 + 131072);
        int c = j & 1023;
        hg[j] = (c < 256) ? b_h2h[c] : b_hh[c - 256];   // hg for s=0 (hidden=0)
    }
}

// ================= batch_H fp32 -> bf16 =================
__global__ __launch_bounds__(256)
void conv_a16(const float* __restrict__ src, ushort_t* __restrict__ dst, int n8) {
    int i = blockIdx.x * 256 + threadIdx.x;
    const int stride = gridDim.x * 256;
    for (; i < n8; i += stride) {
        float4 v0 = ((const float4*)src)[2 * i];
        float4 v1 = ((const float4*)src)[2 * i + 1];
        ushort8v o;
        o[0] = f2bf_rne(v0.x); o[1] = f2bf_rne(v0.y);
        o[2] = f2bf_rne(v0.z); o[3] = f2bf_rne(v0.w);
        o[4] = f2bf_rne(v1.x); o[5] = f2bf_rne(v1.y);
        o[6] = f2bf_rne(v1.z); o[7] = f2bf_rne(v1.w);
        ((ushort8v*)dst)[i] = o;
    }
}

// LDS swizzle (validated): dense 32-ushort rows, XOR quad index
__device__ __forceinline__ int swz(int row, int col8) {
    return (row * 32 + col8 * 8) ^ ((row & 7) << 3);
}

// ================= MFMA GEMM -> split outputs HW16[M][768], Hp16[M][256] (round-11 version) =================
__global__ __launch_bounds__(256)
void hwhp_mfma(const ushort_t* __restrict__ A16,
               const ushort_t* __restrict__ B16,
               ushort_t* __restrict__ HW16,
               ushort_t* __restrict__ Hp16) {
    __shared__ ushort_t As[128 * 32];
    __shared__ ushort_t Bs[128 * 32];
    const int wgid = blockIdx.x;
    const int mt = (wgid & 7) + ((wgid >> 6) << 3);
    const int nt = (wgid >> 3) & 7;
    const int bm = mt * 128, bn = nt * 128;
    const int tid = threadIdx.x;
    const int wid = tid >> 6, lane = tid & 63;
    const int wr = wid >> 1, wc = wid & 1;
    const int sr = tid >> 2, sq = tid & 3;
    f32x4 acc[4][4] = {};
    const int l15 = lane & 15, lhi = lane >> 4;
    for (int k0 = 0; k0 < 512; k0 += 32) {
        ushort8v a0 = *(const ushort8v*)(A16 + (size_t)(bm + sr) * 512 + k0 + sq * 8);
        ushort8v a1 = *(const ushort8v*)(A16 + (size_t)(bm + sr + 64) * 512 + k0 + sq * 8);
        ushort8v b0 = *(const ushort8v*)(B16 + (size_t)(bn + sr) * 512 + k0 + sq * 8);
        ushort8v b1 = *(const ushort8v*)(B16 + (size_t)(bn + sr + 64) * 512 + k0 + sq * 8);
        __syncthreads();
        *(ushort8v*)(&As[swz(sr, sq)]) = a0;
        *(ushort8v*)(&As[swz(sr + 64, sq)]) = a1;
        *(ushort8v*)(&Bs[swz(sr, sq)]) = b0;
        *(ushort8v*)(&Bs[swz(sr + 64, sq)]) = b1;
        __syncthreads();
        short8v af[4], bfr[4];
#pragma unroll
        for (int i = 0; i < 4; ++i) {
            int arow = wr * 64 + i * 16 + l15;
            af[i] = *(const short8v*)(&As[swz(arow, lhi)]);
            int brow = wc * 64 + i * 16 + l15;
            bfr[i] = *(const short8v*)(&Bs[swz(brow, lhi)]);
        }
#pragma unroll
        for (int i = 0; i < 4; ++i)
#pragma unroll
            for (int j = 0; j < 4; ++j)
                acc[i][j] = __builtin_amdgcn_mfma_f32_16x16x32_bf16(af[i], bfr[j], acc[i][j], 0, 0, 0);
    }
    const int cr0 = bm + wr * 64 + lhi * 4;
    const int cc0 = bn + wc * 64 + l15;
    const bool isHW = (bn < 768);
    ushort_t* outp = isHW ? HW16 : Hp16;
    const int ld = isHW ? 768 : 256;
    const int coff = isHW ? 0 : 768;
#pragma unroll
    for (int i = 0; i < 4; ++i)
#pragma unroll
        for (int j = 0; j < 4; ++j)
#pragma unroll
            for (int p = 0; p < 4; ++p)
                outp[(size_t)(cr0 + i * 16 + p) * ld + (cc0 + j * 16 - coff)] = f2bf_rne(acc[i][j][p]);
}

// ================= per-step hg GEMM (validated) =================
__global__ __launch_bounds__(256)
void hg_mfma(const ushort_t* __restrict__ H16,    // [512][256] bf16
             const ushort_t* __restrict__ W16,    // [1024][256] bf16
             const float* __restrict__ bcat,      // [1024]
             float* __restrict__ hg) {            // [512][1024]
    __shared__ ushort_t As[128 * 32];
    __shared__ ushort_t Bs[128 * 32];
    const int wgid = blockIdx.x;                  // 32 blocks: 4 mt x 8 nt
    const int mt = wgid >> 3;
    const int nt = wgid & 7;
    const int bm = mt * 128, bn = nt * 128;
    const int tid = threadIdx.x;
    const int wid = tid >> 6, lane = tid & 63;
    const int wr = wid >> 1, wc = wid & 1;
    const int sr = tid >> 2, sq = tid & 3;
    f32x4 acc[4][4] = {};
    const int l15 = lane & 15, lhi = lane >> 4;
    for (int k0 = 0; k0 < 256; k0 += 32) {
        ushort8v a0 = *(const ushort8v*)(H16 + (size_t)(bm + sr) * 256 + k0 + sq * 8);
        ushort8v a1 = *(const ushort8v*)(H16 + (size_t)(bm + sr + 64) * 256 + k0 + sq * 8);
        ushort8v b0 = *(const ushort8v*)(W16 + (size_t)(bn + sr) * 256 + k0 + sq * 8);
        ushort8v b1 = *(const ushort8v*)(W16 + (size_t)(bn + sr + 64) * 256 + k0 + sq * 8);
        __syncthreads();
        *(ushort8v*)(&As[swz(sr, sq)]) = a0;
        *(ushort8v*)(&As[swz(sr + 64, sq)]) = a1;
        *(ushort8v*)(&Bs[swz(sr, sq)]) = b0;
        *(ushort8v*)(&Bs[swz(sr + 64, sq)]) = b1;
        __syncthreads();
        short8v af[4], bfr[4];
#pragma unroll
        for (int i = 0; i < 4; ++i) {
            int arow = wr * 64 + i * 16 + l15;
            af[i] = *(const short8v*)(&As[swz(arow, lhi)]);
            int brow = wc * 64 + i * 16 + l15;
            bfr[i] = *(const short8v*)(&Bs[swz(brow, lhi)]);
        }
#pragma unroll
        for (int i = 0; i < 4; ++i)
#pragma unroll
            for (int j = 0; j < 4; ++j)
                acc[i][j] = __builtin_amdgcn_mfma_f32_16x16x32_bf16(af[i], bfr[j], acc[i][j], 0, 0, 0);
    }
    const int cr0 = bm + wr * 64 + lhi * 4;
    const int cc0 = bn + wc * 64 + l15;
#pragma unroll
    for (int j = 0; j < 4; ++j) {
        const int c = cc0 + j * 16;
        const float bj = bcat[c];
#pragma unroll
        for (int i = 0; i < 4; ++i)
#pragma unroll
            for (int p = 0; p < 4; ++p)
                hg[(size_t)(cr0 + i * 16 + p) * 1024 + c] = acc[i][j][p] + bj;
    }
}

// ================= per-step fused (round-11 body; NEW: launch_bounds(1024,8) -> 2 blocks/CU) =================
__global__ __launch_bounds__(1024, 8)
void step_fused(const ushort_t* __restrict__ HW16,    // [M][768] bf16
                const ushort_t* __restrict__ Hp16,    // [M][256] bf16
                const float* __restrict__ hg,         // [B][1024] fp32 (h_proj | gh)
                const float* __restrict__ WembT,      // [96][768]
                const ushort_t* __restrict__ Wgen16,  // [96][256]
                const float* __restrict__ Wscore,
                const float* __restrict__ b_gen,
                const int* __restrict__ text,
                int s,
                float* __restrict__ hidden,           // [B][256] fp32 in/out
                ushort_t* __restrict__ hidden16,      // [B][256] bf16 out
                float* __restrict__ out) {
    const int b = blockIdx.x;
    const int tid = threadIdx.x;   // 1024
    const int wave = tid >> 6, lane = tid & 63;

    __shared__ __align__(16) float hp[HID];
    __shared__ __align__(16) float wsc[HID];
    __shared__ __align__(16) float parts[6144];   // 24 KB (pass3: 8x768)
    __shared__ __align__(16) float gi_l[G3];
    __shared__ __align__(16) float sh[HID];
    __shared__ float es[TLEN];
    __shared__ float al[TLEN];
    __shared__ float red[16];

    const size_t rowbase = (size_t)b * TLEN;
    if (tid < 256) {
        hp[tid] = hg[(size_t)b * 1024 + tid];
        wsc[tid] = Wscore[tid];
    }
    __syncthreads();

    // ---- pass 1: scores; full wave per t; Hp rows 512B contiguous
#pragma unroll
    for (int i = 0; i < 8; ++i) {
        int t = i * 16 + wave;
        ushort4 hv = *(const ushort4*)(Hp16 + (rowbase + t) * 256 + lane * 4);
        float4 hpv = *(const float4*)(&hp[lane * 4]);
        float4 wv = *(const float4*)(&wsc[lane * 4]);
        float sc = fast_tanh(bf2f(hv.x) + hpv.x) * wv.x
                 + fast_tanh(bf2f(hv.y) + hpv.y) * wv.y
                 + fast_tanh(bf2f(hv.z) + hpv.z) * wv.z
                 + fast_tanh(bf2f(hv.w) + hpv.w) * wv.w;
#pragma unroll
        for (int off = 32; off >= 1; off >>= 1) sc += __shfl_xor(sc, off);
        if (lane == 0) es[t] = sc;
    }
    __syncthreads();
    // ---- pass 2: softmax (threads 0..127)
    float ev = 0.f, p = 0.f;
    if (tid < TLEN) {
        ev = es[tid];
        float mx = ev;
#pragma unroll
        for (int off = 32; off >= 1; off >>= 1) mx = fmaxf(mx, __shfl_xor(mx, off));
        if (lane == 0) red[wave] = mx;
    }
    __syncthreads();
    if (tid < TLEN) {
        float m = fmaxf(red[0], red[1]);
        p = __expf(ev - m);
        float sm = p;
#pragma unroll
        for (int off = 32; off >= 1; off >>= 1) sm += __shfl_xor(sm, off);
        if (lane == 0) red[8 + wave] = sm;
    }
    __syncthreads();
    if (tid < TLEN) al[tid] = p / (red[8] + red[9]);
    __syncthreads();
    // ---- pass 3: gi partials; 8 t-groups x 96 col-quads on HW rows
    {
        const int tg = tid >> 7;
        const int cq = tid & 127;
        if (cq < 96) {
            float a0 = 0.f, a1 = 0.f, a2 = 0.f, a3 = 0.f;
            float a4 = 0.f, a5 = 0.f, a6 = 0.f, a7 = 0.f;
            const ushort_t* base = HW16 + (rowbase + tg * 16) * 768 + cq * 8;
            const float* alh = &al[tg * 16];
#pragma unroll 4
            for (int i = 0; i < 16; ++i) {
                ushort8v v = *(const ushort8v*)(base + (size_t)i * 768);
                float a = alh[i];
                a0 = fmaf(a, bf2f(v[0]), a0);
                a1 = fmaf(a, bf2f(v[1]), a1);
                a2 = fmaf(a, bf2f(v[2]), a2);
                a3 = fmaf(a, bf2f(v[3]), a3);
                a4 = fmaf(a, bf2f(v[4]), a4);
                a5 = fmaf(a, bf2f(v[5]), a5);
                a6 = fmaf(a, bf2f(v[6]), a6);
                a7 = fmaf(a, bf2f(v[7]), a7);
            }
            float* pr = &parts[tg * 768 + cq * 8];
            pr[0] = a0; pr[1] = a1; pr[2] = a2; pr[3] = a3;
            pr[4] = a4; pr[5] = a5; pr[6] = a6; pr[7] = a7;
        }
    }
    __syncthreads();
    if (tid < G3) {
        float g = parts[tid] + parts[768 + tid] + parts[1536 + tid] + parts[2304 + tid]
                + parts[3072 + tid] + parts[3840 + tid] + parts[4608 + tid] + parts[5376 + tid];
        gi_l[tid] = g;
    }
    __syncthreads();
    // ---- pass 4: GRU gates (threads 0..255) -> sh, hidden, hidden16
    if (tid < 256) {
        const int ch = text[b * STEPS + s];
        const float* em = WembT + (size_t)ch * G3;
        const float* ghb = hg + (size_t)b * 1024 + 256;
        float ir = gi_l[tid]       + em[tid]       + ghb[tid];
        float iz = gi_l[256 + tid] + em[256 + tid] + ghb[256 + tid];
        float in_ = gi_l[512 + tid] + em[512 + tid];
        float hn = ghb[512 + tid];
        float rr = fast_sigmoid(ir);
        float zz = fast_sigmoid(iz);
        float nn = fast_tanh(in_ + rr * hn);
        float nh = (1.f - zz) * nn + zz * hidden[(size_t)b * HID + tid];
        hidden[(size_t)b * HID + tid] = nh;
        hidden16[(size_t)b * HID + tid] = f2bf_rne(nh);
        sh[tid] = nh;
    }
    __syncthreads();
    // ---- pass 5: generator (threads 0..95)
    if (tid < NCLS) {
        const ushort_t* wrow = Wgen16 + (size_t)tid * HID;
        float acc = b_gen[tid];
#pragma unroll 4
        for (int k = 0; k < HID; k += 8) {
            ushort8v w8 = *(const ushort8v*)(wrow + k);
            acc = fmaf(sh[k],     bf2f(w8[0]), acc);
            acc = fmaf(sh[k + 1], bf2f(w8[1]), acc);
            acc = fmaf(sh[k + 2], bf2f(w8[2]), acc);
            acc = fmaf(sh[k + 3], bf2f(w8[3]), acc);
            acc = fmaf(sh[k + 4], bf2f(w8[4]), acc);
            acc = fmaf(sh[k + 5], bf2f(w8[5]), acc);
            acc = fmaf(sh[k + 6], bf2f(w8[6]), acc);
            acc = fmaf(sh[k + 7], bf2f(w8[7]), acc);
        }
        out[((size_t)b * STEPS + s) * NCLS + tid] = acc;
    }
}

// ================= generic fp32 GEMM (fallback) =================
template <typename OutT>
__device__ __forceinline__ void store_c(OutT* p, float v);
template <> __device__ __forceinline__ void store_c<float>(float* p, float v) { *p = v; }
template <> __device__ __forceinline__ void store_c<ushort_t>(ushort_t* p, float v) { *p = f2bf_rne(v); }

template <typename OutT>
__global__ __launch_bounds__(256)
void gemm_nt(const float* __restrict__ A, int lda,
             const float* __restrict__ Bw, int ldb,
             OutT* __restrict__ Cc, int ldc,
             const float* __restrict__ bias,
             int M, int N, int K) {
    __shared__ float As[BK][LDS_STRIDE];
    __shared__ float Bs[BK][LDS_STRIDE];
    const int tid = threadIdx.x;
    const int bm = blockIdx.x * BM;
    const int bn = blockIdx.y * BN;
    const int tx = tid & 15, ty = tid >> 4;
    const int lr = tid >> 2;
    const int lc = (tid & 3) << 2;
    float acc[4][4] = {};
    const int gr = bm + lr;
    const int gn = bn + lr;
    const float* Arow = A + (size_t)gr * lda;
    const float* Brow = Bw + (size_t)gn * ldb;
    for (int k0 = 0; k0 < K; k0 += BK) {
        float4 va = make_float4(0.f, 0.f, 0.f, 0.f);
        float4 vb = make_float4(0.f, 0.f, 0.f, 0.f);
        if (gr < M) va = *(const float4*)(Arow + k0 + lc);
        if (gn < N) vb = *(const float4*)(Brow + k0 + lc);
        As[lc + 0][lr] = va.x; As[lc + 1][lr] = va.y;
        As[lc + 2][lr] = va.z; As[lc + 3][lr] = va.w;
        Bs[lc + 0][lr] = vb.x; Bs[lc + 1][lr] = vb.y;
        Bs[lc + 2][lr] = vb.z; Bs[lc + 3][lr] = vb.w;
        __syncthreads();
#pragma unroll
        for (int k = 0; k < BK; ++k) {
            float4 a4 = *(const float4*)(&As[k][ty << 2]);
            float4 b4 = *(const float4*)(&Bs[k][tx << 2]);
            float a[4] = {a4.x, a4.y, a4.z, a4.w};
            float b[4] = {b4.x, b4.y, b4.z, b4.w};
#pragma unroll
            for (int i = 0; i < 4; ++i)
#pragma unroll
                for (int j = 0; j < 4; ++j)
                    acc[i][j] = fmaf(a[i], b[j], acc[i][j]);
        }
        __syncthreads();
    }
#pragma unroll
    for (int i = 0; i < 4; ++i) {
        int m = bm + (ty << 2) + i;
        if (m >= M) continue;
#pragma unroll
        for (int j = 0; j < 4; ++j) {
            int n = bn + (tx << 2) + j;
            if (n < N) store_c(&Cc[(size_t)m * ldc + n], acc[i][j] + (bias ? bias[n] : 0.f));
        }
    }
}

// ================= fallback kernels (round-3 Plan B, validated) =================
__global__ __launch_bounds__(256)
void prep_wcat(const float* __restrict__ W_h2h, const float* __restrict__ W_hh,
               const float* __restrict__ b_h2h, const float* __restrict__ b_hh,
               float* __restrict__ Wcat, float* __restrict__ bcat,
               float* __restrict__ hidden) {
    int idx = blockIdx.x * 256 + threadIdx.x;
    int r = idx >> 8, c = idx & 255;
    Wcat[idx] = (r < 256) ? W_h2h[r * 256 + c] : W_hh[(r - 256) * 256 + c];
    if (idx < 1024) bcat[idx] = (idx < 256) ? b_h2h[idx] : b_hh[idx - 256];
    if (idx < BATCH * HID) hidden[idx] = 0.f;
}

template <typename HT>
__global__ __launch_bounds__(256)
void attn_step(const HT* __restrict__ Hproj,
               const float* __restrict__ batchH,
               const float* __restrict__ hg,
               const float* __restrict__ Wscore,
               float* __restrict__ context) {
    const int b = blockIdx.x;
    const int tid = threadIdx.x;
    __shared__ float hp[HID];
    __shared__ float wsc[HID];
    __shared__ float es[TLEN];
    __shared__ float red[16];
    hp[tid] = hg[b * 1024 + tid];
    wsc[tid] = Wscore[tid];
    __syncthreads();
    const int wave = tid >> 6;
    const int lane = tid & 63;
    const HT* Hp = Hproj + (size_t)b * TLEN * HID;
    for (int t = wave; t < TLEN; t += 4) {
        float x0, x1, x2, x3;
        if constexpr (sizeof(HT) == 4) {
            float4 hv = *(const float4*)((const float*)Hp + (size_t)t * HID + (lane << 2));
            x0 = hv.x; x1 = hv.y; x2 = hv.z; x3 = hv.w;
        } else {
            ushort4 hv = *(const ushort4*)((const ushort_t*)Hp + (size_t)t * HID + (lane << 2));
            x0 = bf2f(hv.x); x1 = bf2f(hv.y); x2 = bf2f(hv.z); x3 = bf2f(hv.w);
        }
        float4 hpv = *(const float4*)(&hp[lane << 2]);
        float4 wv = *(const float4*)(&wsc[lane << 2]);
        float sc = fast_tanh(x0 + hpv.x) * wv.x
                 + fast_tanh(x1 + hpv.y) * wv.y
                 + fast_tanh(x2 + hpv.z) * wv.z
                 + fast_tanh(x3 + hpv.w) * wv.w;
#pragma unroll
        for (int off = 32; off >= 1; off >>= 1) sc += __shfl_xor(sc, off);
        if (lane == 0) es[t] = sc;
    }
    __syncthreads();
    float e = (tid < TLEN) ? es[tid] : -INFINITY;
    float m = e;
#pragma unroll
    for (int off = 32; off >= 1; off >>= 1) m = fmaxf(m, __shfl_xor(m, off));
    if (lane == 0) red[wave] = m;
    __syncthreads();
    m = fmaxf(fmaxf(red[0], red[1]), fmaxf(red[2], red[3]));
    float p = (tid < TLEN) ? __expf(e - m) : 0.f;
    float ss = p;
#pragma unroll
    for (int off = 32; off >= 1; off >>= 1) ss += __shfl_xor(ss, off);
    if (lane == 0) red[8 + wave] = ss;
    __syncthreads();
    float denom = red[8] + red[9] + red[10] + red[11];
    if (tid < TLEN) es[tid] = p / denom;
    __syncthreads();
    const float* Hb = batchH + (size_t)b * TLEN * DIN;
    float acc0 = 0.f, acc1 = 0.f;
#pragma unroll 4
    for (int t = 0; t < TLEN; ++t) {
        float a = es[t];
        acc0 = fmaf(a, Hb[(size_t)t * DIN + tid], acc0);
        acc1 = fmaf(a, Hb[(size_t)t * DIN + HID + tid], acc1);
    }
    context[(size_t)b * DIN + tid] = acc0;
    context[(size_t)b * DIN + HID + tid] = acc1;
}

__global__ __launch_bounds__(256)
void gru_gate_gen(const float* __restrict__ gi,
                  const float* __restrict__ hg,
                  float* __restrict__ hidden,
                  float* __restrict__ out,
                  const int* __restrict__ text,
                  int s,
                  const float* __restrict__ W_ih,
                  const float* __restrict__ W_gen,
                  const float* __restrict__ b_gen) {
    const int b = blockIdx.x;
    const int h = threadIdx.x;
    __shared__ float sh[HID];
    const int ch = text[b * STEPS + s];
    const float* gib = gi + (size_t)b * G3;
    const float* ghb = hg + (size_t)b * 1024 + 256;
    float ir = gib[h]        + W_ih[(size_t)h * GRUIN + DIN + ch];
    float iz = gib[256 + h]  + W_ih[(size_t)(256 + h) * GRUIN + DIN + ch];
    float in_ = gib[512 + h] + W_ih[(size_t)(512 + h) * GRUIN + DIN + ch];
    float hr = ghb[h];
    float hz = ghb[256 + h];
    float hn = ghb[512 + h];
    float r = fast_sigmoid(ir + hr);
    float z = fast_sigmoid(iz + hz);
    float n = fast_tanh(in_ + r * hn);
    float hprev = hidden[b * HID + h];
    float nh = (1.f - z) * n + z * hprev;
    hidden[b * HID + h] = nh;
    sh[h] = nh;
    __syncthreads();
    if (h < NCLS) {
        const float* wg = W_gen + (size_t)h * HID;
        float acc = b_gen[h];
#pragma unroll 4
        for (int k = 0; k < HID; k += 4) {
            float4 w4 = *(const float4*)(wg + k);
            acc = fmaf(sh[k], w4.x, acc);
            acc = fmaf(sh[k + 1], w4.y, acc);
            acc = fmaf(sh[k + 2], w4.z, acc);
            acc = fmaf(sh[k + 3], w4.w, acc);
        }
        out[((size_t)b * STEPS + s) * NCLS + h] = acc;
    }
}

extern "C" void kernel_launch(void* const* d_in, const int* in_sizes, int n_in,
                              void* d_out, int out_size, void* d_ws, size_t ws_size,
                              hipStream_t stream) {
    const float* batch_H = (const float*)d_in[0];
    const int* text      = (const int*)d_in[1];
    const float* W_i2h   = (const float*)d_in[3];
    const float* W_h2h   = (const float*)d_in[4];
    const float* b_h2h   = (const float*)d_in[5];
    const float* W_score = (const float*)d_in[6];
    const float* W_ih    = (const float*)d_in[7];
    const float* W_hh    = (const float*)d_in[8];
    const float* b_ih    = (const float*)d_in[9];
    const float* b_hh    = (const float*)d_in[10];
    const float* W_gen   = (const float*)d_in[11];
    const float* b_gen   = (const float*)d_in[12];
    float* out = (float*)d_out;
    char* ws = (char*)d_ws;

    const size_t M = (size_t)BATCH * TLEN;              // 65536
    const size_t nBH = M * DIN;
    // workspace layout (bytes) — identical to rounds 11/13
    const size_t hw_off     = 0;                        // HW16:  100,663,296
    const size_t hp_off     = 100663296;                // Hp16:   33,554,432
    const size_t a16_off    = hp_off + 33554432;        // A16:    67,108,864
    const size_t b16cat_off = a16_off + 67108864;       // 1,048,576
    const size_t wcat_off   = b16cat_off + 1048576;     // 524,288
    const size_t wembT_off  = wcat_off + 524288;        // 294,912
    const size_t wgen16_off = wembT_off + 294912;       // 49,152
    const size_t bcat_off   = wgen16_off + 49152;       // 4,096
    const size_t hg_off     = bcat_off + 4096;          // 2,097,152
    const size_t hidden_off = hg_off + 2097152;         // 524,288
    const size_t h16_off    = hidden_off + 524288;      // 262,144
    const size_t need_new   = h16_off + 262144;         // ~206.2 MB

    if (ws_size >= need_new) {
        ushort_t* HW16     = (ushort_t*)(ws + hw_off);
        ushort_t* Hp16     = (ushort_t*)(ws + hp_off);
        ushort_t* A16      = (ushort_t*)(ws + a16_off);
        ushort_t* B16cat   = (ushort_t*)(ws + b16cat_off);
        ushort_t* Wcat16   = (ushort_t*)(ws + wcat_off);
        float*    WembT    = (float*)(ws + wembT_off);
        ushort_t* Wgen16   = (ushort_t*)(ws + wgen16_off);
        float*    bcat     = (float*)(ws + bcat_off);
        float*    hg       = (float*)(ws + hg_off);
        float*    hidden   = (float*)(ws + hidden_off);
        ushort_t* hidden16 = (ushort_t*)(ws + h16_off);

        hipLaunchKernelGGL(prep_all, dim3(6020), dim3(256), 0, stream,
                           W_h2h, W_hh, W_ih, W_i2h, b_ih, b_h2h, b_hh, W_gen,
                           Wcat16, B16cat, WembT, Wgen16, bcat, hidden, hg);
        hipLaunchKernelGGL(conv_a16, dim3(2048), dim3(256), 0, stream,
                           batch_H, A16, (int)(nBH / 8));
        hipLaunchKernelGGL(hwhp_mfma, dim3((M / 128) * 8), dim3(256), 0, stream,
                           A16, B16cat, HW16, Hp16);
        for (int s = 0; s < STEPS; ++s) {
            hipLaunchKernelGGL(step_fused, dim3(BATCH), dim3(1024), 0, stream,
                               HW16, Hp16, hg, WembT, Wgen16, W_score,
                               b_gen, text, s, hidden, hidden16, out);
            if (s < STEPS - 1) {
                hipLaunchKernelGGL(hg_mfma, dim3(32), dim3(256), 0, stream,
                                   hidden16, Wcat16, bcat, hg);
            }
        }
        return;
    }

    // ---------------- fallback: round-3 Plan B ----------------
    const size_t nHp = M * HID;
    const size_t small_floats = (size_t)BATCH * HID + BATCH * 1024 + BATCH * DIN
                              + BATCH * G3 + 1024 * HID + 1024;
    const size_t need_B32 = nHp * 4 + small_floats * 4;
    const bool use_fp32 = (ws_size >= need_B32);
    const size_t hp_bytes = use_fp32 ? nHp * 4 : nHp * 2;
    void* Hproj = (void*)ws;
    float* hiddenB = (float*)(ws + hp_bytes);
    float* hgB     = hiddenB + BATCH * HID;
    float* context = hgB + BATCH * 1024;
    float* gi      = context + BATCH * DIN;
    float* Wcat    = gi + BATCH * G3;
    float* bcatB   = Wcat + 1024 * HID;

    hipLaunchKernelGGL(prep_wcat, dim3(1024), dim3(256), 0, stream,
                       W_h2h, W_hh, b_h2h, b_hh, Wcat, bcatB, hiddenB);
    if (use_fp32) {
        hipLaunchKernelGGL(gemm_nt<float>, dim3(M / BM, HID / BN), dim3(256), 0, stream,
                           batch_H, DIN, W_i2h, DIN, (float*)Hproj, HID, (const float*)nullptr,
                           (int)M, HID, DIN);
    } else {
        hipLaunchKernelGGL(gemm_nt<ushort_t>, dim3(M / BM, HID / BN), dim3(256), 0, stream,
                           batch_H, DIN, W_i2h, DIN, (ushort_t*)Hproj, HID, (const float*)nullptr,
                           (int)M, HID, DIN);
    }
    for (int s = 0; s < STEPS; ++s) {
        hipLaunchKernelGGL(gemm_nt<float>, dim3(BATCH / BM, 1024 / BN), dim3(256), 0, stream,
                           hiddenB, HID, Wcat, HID, hgB, 1024, bcatB, BATCH, 1024, HID);
        if (use_fp32) {
            hipLaunchKernelGGL(attn_step<float>, dim3(BATCH), dim3(256), 0, stream,
                               (const float*)Hproj, batch_H, hgB, W_score, context);
        } else {
            hipLaunchKernelGGL(attn_step<ushort_t>, dim3(BATCH), dim3(256), 0, stream,
                               (const ushort_t*)Hproj, batch_H, hgB, W_score, context);
        }
        hipLaunchKernelGGL(gemm_nt<float>, dim3(BATCH / BM, G3 / BN), dim3(256), 0, stream,
                           context, DIN, W_ih, GRUIN, gi, G3, b_ih, BATCH, G3, DIN);
        hipLaunchKernelGGL(gru_gate_gen, dim3(BATCH), dim3(HID), 0, stream,
                           gi, hgB, hiddenB, out, text, s, W_ih, W_gen, b_gen);
    }
}

// Round 16
// 1030.553 us; speedup vs baseline: 1.8968x; 1.0401x over previous
//
#include <hip/hip_runtime.h>

#define BATCH 512
#define TLEN 128
#define DIN 512
#define HID 256
#define NCLS 96
#define STEPS 26
#define GRUIN 608
#define G3 768

#define BM 64
#define BN 64
#define BK 16
#define LDS_STRIDE 68

typedef unsigned short ushort_t;
typedef __attribute__((ext_vector_type(8))) short short8v;
typedef __attribute__((ext_vector_type(4))) float f32x4;
typedef __attribute__((ext_vector_type(8))) unsigned short ushort8v;

__device__ __forceinline__ float fast_tanh(float x) {
    return 1.f - 2.f / (__expf(2.f * x) + 1.f);
}
__device__ __forceinline__ float fast_sigmoid(float x) {
    return 1.f / (1.f + __expf(-x));
}
__device__ __forceinline__ ushort_t f2bf_rne(float f) {
    unsigned int u = __float_as_uint(f);
    unsigned int r = (u + 0x7FFFu + ((u >> 16) & 1u)) >> 16;
    return (ushort_t)r;
}
__device__ __forceinline__ float bf2f(ushort_t h) {
    return __uint_as_float(((unsigned int)h) << 16);
}

// ================= one-time prep (validated) =================
__global__ __launch_bounds__(256)
void prep_all(const float* __restrict__ W_h2h, const float* __restrict__ W_hh,
              const float* __restrict__ W_ih, const float* __restrict__ W_i2h,
              const float* __restrict__ b_ih, const float* __restrict__ b_h2h,
              const float* __restrict__ b_hh, const float* __restrict__ W_gen,
              ushort_t* __restrict__ Wcat16, ushort_t* __restrict__ B16cat,
              float* __restrict__ WembT, ushort_t* __restrict__ Wgen16,
              float* __restrict__ bcat, float* __restrict__ hidden,
              float* __restrict__ hg) {
    int idx = blockIdx.x * 256 + threadIdx.x;
    if (idx < 262144) {
        int n = idx >> 8, k = idx & 255;
        float v = (n < 256) ? W_h2h[n * 256 + k] : W_hh[(size_t)(n - 256) * 256 + k];
        Wcat16[idx] = f2bf_rne(v);
    } else if (idx < 262144 + 524288) {
        int j = idx - 262144;
        int r = j >> 9, c = j & 511;
        float v = (r < 768) ? W_ih[(size_t)r * GRUIN + c] : W_i2h[(size_t)(r - 768) * 512 + c];
        B16cat[j] = f2bf_rne(v);
    } else if (idx < 262144 + 524288 + 73728) {
        int j = idx - (262144 + 524288);
        int ch = j / 768, jj = j - ch * 768;
        WembT[j] = W_ih[(size_t)jj * GRUIN + 512 + ch] + b_ih[jj];
    } else if (idx < 262144 + 524288 + 73728 + 24576) {
        int j = idx - (262144 + 524288 + 73728);
        Wgen16[j] = f2bf_rne(W_gen[j]);
    } else if (idx < 262144 + 524288 + 73728 + 24576 + 1024) {
        int j = idx - (262144 + 524288 + 73728 + 24576);
        bcat[j] = (j < 256) ? b_h2h[j] : b_hh[j - 256];
    } else if (idx < 262144 + 524288 + 73728 + 24576 + 1024 + 131072) {
        int j = idx - (262144 + 524288 + 73728 + 24576 + 1024);
        hidden[j] = 0.f;
    } else if (idx < 262144 + 524288 + 73728 + 24576 + 1024 + 131072 + 524288) {
        int j = idx - (262144 + 524288 + 73728 + 24576 + 1024 + 131072);
        int c = j & 1023;
        hg[j] = (c < 256) ? b_h2h[c] : b_hh[c - 256];   // hg for s=0 (hidden=0)
    }
}

// ================= batch_H fp32 -> bf16 =================
__global__ __launch_bounds__(256)
void conv_a16(const float* __restrict__ src, ushort_t* __restrict__ dst, int n8) {
    int i = blockIdx.x * 256 + threadIdx.x;
    const int stride = gridDim.x * 256;
    for (; i < n8; i += stride) {
        float4 v0 = ((const float4*)src)[2 * i];
        float4 v1 = ((const float4*)src)[2 * i + 1];
        ushort8v o;
        o[0] = f2bf_rne(v0.x); o[1] = f2bf_rne(v0.y);
        o[2] = f2bf_rne(v0.z); o[3] = f2bf_rne(v0.w);
        o[4] = f2bf_rne(v1.x); o[5] = f2bf_rne(v1.y);
        o[6] = f2bf_rne(v1.z); o[7] = f2bf_rne(v1.w);
        ((ushort8v*)dst)[i] = o;
    }
}

// LDS swizzle (validated): dense 32-ushort rows, XOR quad index
__device__ __forceinline__ int swz(int row, int col8) {
    return (row * 32 + col8 * 8) ^ ((row & 7) << 3);
}

// ================= MFMA GEMM -> HW16[M][768], Hp16[M][256] =================
// global_load_lds staging; CORRECTED inverse permutation (round-15 postmortem):
// phys slot l must equal 4*(r ^ ((r>>2)&1)) + (q ^ (r&3))  =>
//   rin  = (l>>2) ^ ((l>>4)&1)
//   qsrc = (l&3) ^ (rin&3)
__global__ __launch_bounds__(256)
void hwhp_mfma(const ushort_t* __restrict__ A16,
               const ushort_t* __restrict__ B16,
               ushort_t* __restrict__ HW16,
               ushort_t* __restrict__ Hp16) {
    __shared__ ushort_t As[128 * 32];
    __shared__ ushort_t Bs[128 * 32];
    const int wgid = blockIdx.x;
    const int mt = (wgid & 7) + ((wgid >> 6) << 3);
    const int nt = (wgid >> 3) & 7;
    const int bm = mt * 128, bn = nt * 128;
    const int tid = threadIdx.x;
    const int wid = tid >> 6, lane = tid & 63;
    const int wr = wid >> 1, wc = wid & 1;
    f32x4 acc[4][4] = {};
    const int l15 = lane & 15, lhi = lane >> 4;
    const int rin = (lane >> 2) ^ ((lane >> 4) & 1);   // corrected
    const int qsrc = (lane & 3) ^ (rin & 3);           // corrected
    for (int k0 = 0; k0 < 512; k0 += 32) {
        __syncthreads();   // prior iteration's LDS reads complete
#pragma unroll
        for (int c = 0; c < 2; ++c) {
            const int chunk = wid + 4 * c;     // 0..7 (16 rows each)
            const int row = chunk * 16 + rin;
            __builtin_amdgcn_global_load_lds(
                (const __attribute__((address_space(1))) void*)(A16 + (size_t)(bm + row) * 512 + k0 + qsrc * 8),
                (__attribute__((address_space(3))) void*)(As + chunk * 512),
                16, 0, 0);
            __builtin_amdgcn_global_load_lds(
                (const __attribute__((address_space(1))) void*)(B16 + (size_t)(bn + row) * 512 + k0 + qsrc * 8),
                (__attribute__((address_space(3))) void*)(Bs + chunk * 512),
                16, 0, 0);
        }
        __syncthreads();   // drains vmcnt before use
        short8v af[4], bfr[4];
#pragma unroll
        for (int i = 0; i < 4; ++i) {
            int arow = wr * 64 + i * 16 + l15;
            af[i] = *(const short8v*)(&As[swz(arow, lhi)]);
            int brow = wc * 64 + i * 16 + l15;
            bfr[i] = *(const short8v*)(&Bs[swz(brow, lhi)]);
        }
#pragma unroll
        for (int i = 0; i < 4; ++i)
#pragma unroll
            for (int j = 0; j < 4; ++j)
                acc[i][j] = __builtin_amdgcn_mfma_f32_16x16x32_bf16(af[i], bfr[j], acc[i][j], 0, 0, 0);
    }
    const int cr0 = bm + wr * 64 + lhi * 4;
    const int cc0 = bn + wc * 64 + l15;
    const bool isHW = (bn < 768);
    ushort_t* outp = isHW ? HW16 : Hp16;
    const int ld = isHW ? 768 : 256;
    const int coff = isHW ? 0 : 768;
#pragma unroll
    for (int i = 0; i < 4; ++i)
#pragma unroll
        for (int j = 0; j < 4; ++j)
#pragma unroll
            for (int p = 0; p < 4; ++p)
                outp[(size_t)(cr0 + i * 16 + p) * ld + (cc0 + j * 16 - coff)] = f2bf_rne(acc[i][j][p]);
}

// ================= per-step hg GEMM: 64 blocks of 64x128 tiles =================
__global__ __launch_bounds__(256)
void hg_mfma(const ushort_t* __restrict__ H16,    // [512][256] bf16
             const ushort_t* __restrict__ W16,    // [1024][256] bf16
             const float* __restrict__ bcat,      // [1024]
             float* __restrict__ hg) {            // [512][1024]
    __shared__ ushort_t As[64 * 32];
    __shared__ ushort_t Bs[128 * 32];
    const int wgid = blockIdx.x;                  // 64 blocks: 8 mt x 8 nt
    const int mt = wgid >> 3;
    const int nt = wgid & 7;
    const int bm = mt * 64, bn = nt * 128;
    const int tid = threadIdx.x;
    const int wid = tid >> 6, lane = tid & 63;
    const int wr = wid >> 1, wc = wid & 1;        // 2x2 waves over 64x128
    const int sr = tid >> 2, sq = tid & 3;
    f32x4 acc[2][4] = {};
    const int l15 = lane & 15, lhi = lane >> 4;
    for (int k0 = 0; k0 < 256; k0 += 32) {
        ushort8v a0 = *(const ushort8v*)(H16 + (size_t)(bm + (sr & 63)) * 256 + k0 + sq * 8);
        ushort8v b0 = *(const ushort8v*)(W16 + (size_t)(bn + sr) * 256 + k0 + sq * 8);
        ushort8v b1 = *(const ushort8v*)(W16 + (size_t)(bn + sr + 64) * 256 + k0 + sq * 8);
        __syncthreads();
        if (sr < 64) *(ushort8v*)(&As[swz(sr, sq)]) = a0;
        *(ushort8v*)(&Bs[swz(sr, sq)]) = b0;
        *(ushort8v*)(&Bs[swz(sr + 64, sq)]) = b1;
        __syncthreads();
        short8v af[2], bfr[4];
#pragma unroll
        for (int i = 0; i < 2; ++i) {
            int arow = wr * 32 + i * 16 + l15;
            af[i] = *(const short8v*)(&As[swz(arow, lhi)]);
        }
#pragma unroll
        for (int j = 0; j < 4; ++j) {
            int brow = wc * 64 + j * 16 + l15;
            bfr[j] = *(const short8v*)(&Bs[swz(brow, lhi)]);
        }
#pragma unroll
        for (int i = 0; i < 2; ++i)
#pragma unroll
            for (int j = 0; j < 4; ++j)
                acc[i][j] = __builtin_amdgcn_mfma_f32_16x16x32_bf16(af[i], bfr[j], acc[i][j], 0, 0, 0);
    }
    const int cr0 = bm + wr * 32 + lhi * 4;
    const int cc0 = bn + wc * 64 + l15;
#pragma unroll
    for (int j = 0; j < 4; ++j) {
        const int c = cc0 + j * 16;
        const float bj = bcat[c];
#pragma unroll
        for (int i = 0; i < 2; ++i)
#pragma unroll
            for (int p = 0; p < 4; ++p)
                hg[(size_t)(cr0 + i * 16 + p) * 1024 + c] = acc[i][j][p] + bj;
    }
}

// ================= per-step fused (round-14, validated; lb(1024,8) -> 2 blocks/CU) =================
__global__ __launch_bounds__(1024, 8)
void step_fused(const ushort_t* __restrict__ HW16,    // [M][768] bf16
                const ushort_t* __restrict__ Hp16,    // [M][256] bf16
                const float* __restrict__ hg,         // [B][1024] fp32 (h_proj | gh)
                const float* __restrict__ WembT,      // [96][768]
                const ushort_t* __restrict__ Wgen16,  // [96][256]
                const float* __restrict__ Wscore,
                const float* __restrict__ b_gen,
                const int* __restrict__ text,
                int s,
                float* __restrict__ hidden,           // [B][256] fp32 in/out
                ushort_t* __restrict__ hidden16,      // [B][256] bf16 out
                float* __restrict__ out) {
    const int b = blockIdx.x;
    const int tid = threadIdx.x;   // 1024
    const int wave = tid >> 6, lane = tid & 63;

    __shared__ __align__(16) float hp[HID];
    __shared__ __align__(16) float wsc[HID];
    __shared__ __align__(16) float parts[6144];   // 24 KB (pass3: 8x768)
    __shared__ __align__(16) float gi_l[G3];
    __shared__ __align__(16) float sh[HID];
    __shared__ float es[TLEN];
    __shared__ float al[TLEN];
    __shared__ float red[16];

    const size_t rowbase = (size_t)b * TLEN;
    if (tid < 256) {
        hp[tid] = hg[(size_t)b * 1024 + tid];
        wsc[tid] = Wscore[tid];
    }
    __syncthreads();

    // ---- pass 1: scores; full wave per t; Hp rows 512B contiguous
#pragma unroll
    for (int i = 0; i < 8; ++i) {
        int t = i * 16 + wave;
        ushort4 hv = *(const ushort4*)(Hp16 + (rowbase + t) * 256 + lane * 4);
        float4 hpv = *(const float4*)(&hp[lane * 4]);
        float4 wv = *(const float4*)(&wsc[lane * 4]);
        float sc = fast_tanh(bf2f(hv.x) + hpv.x) * wv.x
                 + fast_tanh(bf2f(hv.y) + hpv.y) * wv.y
                 + fast_tanh(bf2f(hv.z) + hpv.z) * wv.z
                 + fast_tanh(bf2f(hv.w) + hpv.w) * wv.w;
#pragma unroll
        for (int off = 32; off >= 1; off >>= 1) sc += __shfl_xor(sc, off);
        if (lane == 0) es[t] = sc;
    }
    __syncthreads();
    // ---- pass 2: softmax (threads 0..127)
    float ev = 0.f, p = 0.f;
    if (tid < TLEN) {
        ev = es[tid];
        float mx = ev;
#pragma unroll
        for (int off = 32; off >= 1; off >>= 1) mx = fmaxf(mx, __shfl_xor(mx, off));
        if (lane == 0) red[wave] = mx;
    }
    __syncthreads();
    if (tid < TLEN) {
        float m = fmaxf(red[0], red[1]);
        p = __expf(ev - m);
        float sm = p;
#pragma unroll
        for (int off = 32; off >= 1; off >>= 1) sm += __shfl_xor(sm, off);
        if (lane == 0) red[8 + wave] = sm;
    }
    __syncthreads();
    if (tid < TLEN) al[tid] = p / (red[8] + red[9]);
    __syncthreads();
    // ---- pass 3: gi partials; 8 t-groups x 96 col-quads on HW rows
    {
        const int tg = tid >> 7;
        const int cq = tid & 127;
        if (cq < 96) {
            float a0 = 0.f, a1 = 0.f, a2 = 0.f, a3 = 0.f;
            float a4 = 0.f, a5 = 0.f, a6 = 0.f, a7 = 0.f;
            const ushort_t* base = HW16 + (rowbase + tg * 16) * 768 + cq * 8;
            const float* alh = &al[tg * 16];
#pragma unroll 4
            for (int i = 0; i < 16; ++i) {
                ushort8v v = *(const ushort8v*)(base + (size_t)i * 768);
                float a = alh[i];
                a0 = fmaf(a, bf2f(v[0]), a0);
                a1 = fmaf(a, bf2f(v[1]), a1);
                a2 = fmaf(a, bf2f(v[2]), a2);
                a3 = fmaf(a, bf2f(v[3]), a3);
                a4 = fmaf(a, bf2f(v[4]), a4);
                a5 = fmaf(a, bf2f(v[5]), a5);
                a6 = fmaf(a, bf2f(v[6]), a6);
                a7 = fmaf(a, bf2f(v[7]), a7);
            }
            float* pr = &parts[tg * 768 + cq * 8];
            pr[0] = a0; pr[1] = a1; pr[2] = a2; pr[3] = a3;
            pr[4] = a4; pr[5] = a5; pr[6] = a6; pr[7] = a7;
        }
    }
    __syncthreads();
    if (tid < G3) {
        float g = parts[tid] + parts[768 + tid] + parts[1536 + tid] + parts[2304 + tid]
                + parts[3072 + tid] + parts[3840 + tid] + parts[4608 + tid] + parts[5376 + tid];
        gi_l[tid] = g;
    }
    __syncthreads();
    // ---- pass 4: GRU gates (threads 0..255) -> sh, hidden, hidden16
    if (tid < 256) {
        const int ch = text[b * STEPS + s];
        const float* em = WembT + (size_t)ch * G3;
        const float* ghb = hg + (size_t)b * 1024 + 256;
        float ir = gi_l[tid]       + em[tid]       + ghb[tid];
        float iz = gi_l[256 + tid] + em[256 + tid] + ghb[256 + tid];
        float in_ = gi_l[512 + tid] + em[512 + tid];
        float hn = ghb[512 + tid];
        float rr = fast_sigmoid(ir);
        float zz = fast_sigmoid(iz);
        float nn = fast_tanh(in_ + rr * hn);
        float nh = (1.f - zz) * nn + zz * hidden[(size_t)b * HID + tid];
        hidden[(size_t)b * HID + tid] = nh;
        hidden16[(size_t)b * HID + tid] = f2bf_rne(nh);
        sh[tid] = nh;
    }
    __syncthreads();
    // ---- pass 5: generator (threads 0..95)
    if (tid < NCLS) {
        const ushort_t* wrow = Wgen16 + (size_t)tid * HID;
        float acc = b_gen[tid];
#pragma unroll 4
        for (int k = 0; k < HID; k += 8) {
            ushort8v w8 = *(const ushort8v*)(wrow + k);
            acc = fmaf(sh[k],     bf2f(w8[0]), acc);
            acc = fmaf(sh[k + 1], bf2f(w8[1]), acc);
            acc = fmaf(sh[k + 2], bf2f(w8[2]), acc);
            acc = fmaf(sh[k + 3], bf2f(w8[3]), acc);
            acc = fmaf(sh[k + 4], bf2f(w8[4]), acc);
            acc = fmaf(sh[k + 5], bf2f(w8[5]), acc);
            acc = fmaf(sh[k + 6], bf2f(w8[6]), acc);
            acc = fmaf(sh[k + 7], bf2f(w8[7]), acc);
        }
        out[((size_t)b * STEPS + s) * NCLS + tid] = acc;
    }
}

// ================= generic fp32 GEMM (fallback) =================
template <typename OutT>
__device__ __forceinline__ void store_c(OutT* p, float v);
template <> __device__ __forceinline__ void store_c<float>(float* p, float v) { *p = v; }
template <> __device__ __forceinline__ void store_c<ushort_t>(ushort_t* p, float v) { *p = f2bf_rne(v); }

template <typename OutT>
__global__ __launch_bounds__(256)
void gemm_nt(const float* __restrict__ A, int lda,
             const float* __restrict__ Bw, int ldb,
             OutT* __restrict__ Cc, int ldc,
             const float* __restrict__ bias,
             int M, int N, int K) {
    __shared__ float As[BK][LDS_STRIDE];
    __shared__ float Bs[BK][LDS_STRIDE];
    const int tid = threadIdx.x;
    const int bm = blockIdx.x * BM;
    const int bn = blockIdx.y * BN;
    const int tx = tid & 15, ty = tid >> 4;
    const int lr = tid >> 2;
    const int lc = (tid & 3) << 2;
    float acc[4][4] = {};
    const int gr = bm + lr;
    const int gn = bn + lr;
    const float* Arow = A + (size_t)gr * lda;
    const float* Brow = Bw + (size_t)gn * ldb;
    for (int k0 = 0; k0 < K; k0 += BK) {
        float4 va = make_float4(0.f, 0.f, 0.f, 0.f);
        float4 vb = make_float4(0.f, 0.f, 0.f, 0.f);
        if (gr < M) va = *(const float4*)(Arow + k0 + lc);
        if (gn < N) vb = *(const float4*)(Brow + k0 + lc);
        As[lc + 0][lr] = va.x; As[lc + 1][lr] = va.y;
        As[lc + 2][lr] = va.z; As[lc + 3][lr] = va.w;
        Bs[lc + 0][lr] = vb.x; Bs[lc + 1][lr] = vb.y;
        Bs[lc + 2][lr] = vb.z; Bs[lc + 3][lr] = vb.w;
        __syncthreads();
#pragma unroll
        for (int k = 0; k < BK; ++k) {
            float4 a4 = *(const float4*)(&As[k][ty << 2]);
            float4 b4 = *(const float4*)(&Bs[k][tx << 2]);
            float a[4] = {a4.x, a4.y, a4.z, a4.w};
            float b[4] = {b4.x, b4.y, b4.z, b4.w};
#pragma unroll
            for (int i = 0; i < 4; ++i)
#pragma unroll
                for (int j = 0; j < 4; ++j)
                    acc[i][j] = fmaf(a[i], b[j], acc[i][j]);
        }
        __syncthreads();
    }
#pragma unroll
    for (int i = 0; i < 4; ++i) {
        int m = bm + (ty << 2) + i;
        if (m >= M) continue;
#pragma unroll
        for (int j = 0; j < 4; ++j) {
            int n = bn + (tx << 2) + j;
            if (n < N) store_c(&Cc[(size_t)m * ldc + n], acc[i][j] + (bias ? bias[n] : 0.f));
        }
    }
}

// ================= fallback kernels (round-3 Plan B, validated) =================
__global__ __launch_bounds__(256)
void prep_wcat(const float* __restrict__ W_h2h, const float* __restrict__ W_hh,
               const float* __restrict__ b_h2h, const float* __restrict__ b_hh,
               float* __restrict__ Wcat, float* __restrict__ bcat,
               float* __restrict__ hidden) {
    int idx = blockIdx.x * 256 + threadIdx.x;
    int r = idx >> 8, c = idx & 255;
    Wcat[idx] = (r < 256) ? W_h2h[r * 256 + c] : W_hh[(r - 256) * 256 + c];
    if (idx < 1024) bcat[idx] = (idx < 256) ? b_h2h[idx] : b_hh[idx - 256];
    if (idx < BATCH * HID) hidden[idx] = 0.f;
}

template <typename HT>
__global__ __launch_bounds__(256)
void attn_step(const HT* __restrict__ Hproj,
               const float* __restrict__ batchH,
               const float* __restrict__ hg,
               const float* __restrict__ Wscore,
               float* __restrict__ context) {
    const int b = blockIdx.x;
    const int tid = threadIdx.x;
    __shared__ float hp[HID];
    __shared__ float wsc[HID];
    __shared__ float es[TLEN];
    __shared__ float red[16];
    hp[tid] = hg[b * 1024 + tid];
    wsc[tid] = Wscore[tid];
    __syncthreads();
    const int wave = tid >> 6;
    const int lane = tid & 63;
    const HT* Hp = Hproj + (size_t)b * TLEN * HID;
    for (int t = wave; t < TLEN; t += 4) {
        float x0, x1, x2, x3;
        if constexpr (sizeof(HT) == 4) {
            float4 hv = *(const float4*)((const float*)Hp + (size_t)t * HID + (lane << 2));
            x0 = hv.x; x1 = hv.y; x2 = hv.z; x3 = hv.w;
        } else {
            ushort4 hv = *(const ushort4*)((const ushort_t*)Hp + (size_t)t * HID + (lane << 2));
            x0 = bf2f(hv.x); x1 = bf2f(hv.y); x2 = bf2f(hv.z); x3 = bf2f(hv.w);
        }
        float4 hpv = *(const float4*)(&hp[lane << 2]);
        float4 wv = *(const float4*)(&wsc[lane << 2]);
        float sc = fast_tanh(x0 + hpv.x) * wv.x
                 + fast_tanh(x1 + hpv.y) * wv.y
                 + fast_tanh(x2 + hpv.z) * wv.z
                 + fast_tanh(x3 + hpv.w) * wv.w;
#pragma unroll
        for (int off = 32; off >= 1; off >>= 1) sc += __shfl_xor(sc, off);
        if (lane == 0) es[t] = sc;
    }
    __syncthreads();
    float e = (tid < TLEN) ? es[tid] : -INFINITY;
    float m = e;
#pragma unroll
    for (int off = 32; off >= 1; off >>= 1) m = fmaxf(m, __shfl_xor(m, off));
    if (lane == 0) red[wave] = m;
    __syncthreads();
    m = fmaxf(fmaxf(red[0], red[1]), fmaxf(red[2], red[3]));
    float p = (tid < TLEN) ? __expf(e - m) : 0.f;
    float ss = p;
#pragma unroll
    for (int off = 32; off >= 1; off >>= 1) ss += __shfl_xor(ss, off);
    if (lane == 0) red[8 + wave] = ss;
    __syncthreads();
    float denom = red[8] + red[9] + red[10] + red[11];
    if (tid < TLEN) es[tid] = p / denom;
    __syncthreads();
    const float* Hb = batchH + (size_t)b * TLEN * DIN;
    float acc0 = 0.f, acc1 = 0.f;
#pragma unroll 4
    for (int t = 0; t < TLEN; ++t) {
        float a = es[t];
        acc0 = fmaf(a, Hb[(size_t)t * DIN + tid], acc0);
        acc1 = fmaf(a, Hb[(size_t)t * DIN + HID + tid], acc1);
    }
    context[(size_t)b * DIN + tid] = acc0;
    context[(size_t)b * DIN + HID + tid] = acc1;
}

__global__ __launch_bounds__(256)
void gru_gate_gen(const float* __restrict__ gi,
                  const float* __restrict__ hg,
                  float* __restrict__ hidden,
                  float* __restrict__ out,
                  const int* __restrict__ text,
                  int s,
                  const float* __restrict__ W_ih,
                  const float* __restrict__ W_gen,
                  const float* __restrict__ b_gen) {
    const int b = blockIdx.x;
    const int h = threadIdx.x;
    __shared__ float sh[HID];
    const int ch = text[b * STEPS + s];
    const float* gib = gi + (size_t)b * G3;
    const float* ghb = hg + (size_t)b * 1024 + 256;
    float ir = gib[h]        + W_ih[(size_t)h * GRUIN + DIN + ch];
    float iz = gib[256 + h]  + W_ih[(size_t)(256 + h) * GRUIN + DIN + ch];
    float in_ = gib[512 + h] + W_ih[(size_t)(512 + h) * GRUIN + DIN + ch];
    float hr = ghb[h];
    float hz = ghb[256 + h];
    float hn = ghb[512 + h];
    float r = fast_sigmoid(ir + hr);
    float z = fast_sigmoid(iz + hz);
    float n = fast_tanh(in_ + r * hn);
    float hprev = hidden[b * HID + h];
    float nh = (1.f - z) * n + z * hprev;
    hidden[b * HID + h] = nh;
    sh[h] = nh;
    __syncthreads();
    if (h < NCLS) {
        const float* wg = W_gen + (size_t)h * HID;
        float acc = b_gen[h];
#pragma unroll 4
        for (int k = 0; k < HID; k += 4) {
            float4 w4 = *(const float4*)(wg + k);
            acc = fmaf(sh[k], w4.x, acc);
            acc = fmaf(sh[k + 1], w4.y, acc);
            acc = fmaf(sh[k + 2], w4.z, acc);
            acc = fmaf(sh[k + 3], w4.w, acc);
        }
        out[((size_t)b * STEPS + s) * NCLS + h] = acc;
    }
}

extern "C" void kernel_launch(void* const* d_in, const int* in_sizes, int n_in,
                              void* d_out, int out_size, void* d_ws, size_t ws_size,
                              hipStream_t stream) {
    const float* batch_H = (const float*)d_in[0];
    const int* text      = (const int*)d_in[1];
    const float* W_i2h   = (const float*)d_in[3];
    const float* W_h2h   = (const float*)d_in[4];
    const float* b_h2h   = (const float*)d_in[5];
    const float* W_score = (const float*)d_in[6];
    const float* W_ih    = (const float*)d_in[7];
    const float* W_hh    = (const float*)d_in[8];
    const float* b_ih    = (const float*)d_in[9];
    const float* b_hh    = (const float*)d_in[10];
    const float* W_gen   = (const float*)d_in[11];
    const float* b_gen   = (const float*)d_in[12];
    float* out = (float*)d_out;
    char* ws = (char*)d_ws;

    const size_t M = (size_t)BATCH * TLEN;              // 65536
    const size_t nBH = M * DIN;
    // workspace layout (bytes) — identical to rounds 11/13/14
    const size_t hw_off     = 0;                        // HW16:  100,663,296
    const size_t hp_off     = 100663296;                // Hp16:   33,554,432
    const size_t a16_off    = hp_off + 33554432;        // A16:    67,108,864
    const size_t b16cat_off = a16_off + 67108864;       // 1,048,576
    const size_t wcat_off   = b16cat_off + 1048576;     // 524,288
    const size_t wembT_off  = wcat_off + 524288;        // 294,912
    const size_t wgen16_off = wembT_off + 294912;       // 49,152
    const size_t bcat_off   = wgen16_off + 49152;       // 4,096
    const size_t hg_off     = bcat_off + 4096;          // 2,097,152
    const size_t hidden_off = hg_off + 2097152;         // 524,288
    const size_t h16_off    = hidden_off + 524288;      // 262,144
    const size_t need_new   = h16_off + 262144;         // ~206.2 MB

    if (ws_size >= need_new) {
        ushort_t* HW16     = (ushort_t*)(ws + hw_off);
        ushort_t* Hp16     = (ushort_t*)(ws + hp_off);
        ushort_t* A16      = (ushort_t*)(ws + a16_off);
        ushort_t* B16cat   = (ushort_t*)(ws + b16cat_off);
        ushort_t* Wcat16   = (ushort_t*)(ws + wcat_off);
        float*    WembT    = (float*)(ws + wembT_off);
        ushort_t* Wgen16   = (ushort_t*)(ws + wgen16_off);
        float*    bcat     = (float*)(ws + bcat_off);
        float*    hg       = (float*)(ws + hg_off);
        float*    hidden   = (float*)(ws + hidden_off);
        ushort_t* hidden16 = (ushort_t*)(ws + h16_off);

        hipLaunchKernelGGL(prep_all, dim3(6020), dim3(256), 0, stream,
                           W_h2h, W_hh, W_ih, W_i2h, b_ih, b_h2h, b_hh, W_gen,
                           Wcat16, B16cat, WembT, Wgen16, bcat, hidden, hg);
        hipLaunchKernelGGL(conv_a16, dim3(2048), dim3(256), 0, stream,
                           batch_H, A16, (int)(nBH / 8));
        hipLaunchKernelGGL(hwhp_mfma, dim3((M / 128) * 8), dim3(256), 0, stream,
                           A16, B16cat, HW16, Hp16);
        for (int s = 0; s < STEPS; ++s) {
            hipLaunchKernelGGL(step_fused, dim3(BATCH), dim3(1024), 0, stream,
                               HW16, Hp16, hg, WembT, Wgen16, W_score,
                               b_gen, text, s, hidden, hidden16, out);
            if (s < STEPS - 1) {
                hipLaunchKernelGGL(hg_mfma, dim3(64), dim3(256), 0, stream,
                                   hidden16, Wcat16, bcat, hg);
            }
        }
        return;
    }

    // ---------------- fallback: round-3 Plan B ----------------
    const size_t nHp = M * HID;
    const size_t small_floats = (size_t)BATCH * HID + BATCH * 1024 + BATCH * DIN
                              + BATCH * G3 + 1024 * HID + 1024;
    const size_t need_B32 = nHp * 4 + small_floats * 4;
    const bool use_fp32 = (ws_size >= need_B32);
    const size_t hp_bytes = use_fp32 ? nHp * 4 : nHp * 2;
    void* Hproj = (void*)ws;
    float* hiddenB = (float*)(ws + hp_bytes);
    float* hgB     = hiddenB + BATCH * HID;
    float* context = hgB + BATCH * 1024;
    float* gi      = context + BATCH * DIN;
    float* Wcat    = gi + BATCH * G3;
    float* bcatB   = Wcat + 1024 * HID;

    hipLaunchKernelGGL(prep_wcat, dim3(1024), dim3(256), 0, stream,
                       W_h2h, W_hh, b_h2h, b_hh, Wcat, bcatB, hiddenB);
    if (use_fp32) {
        hipLaunchKernelGGL(gemm_nt<float>, dim3(M / BM, HID / BN), dim3(256), 0, stream,
                           batch_H, DIN, W_i2h, DIN, (float*)Hproj, HID, (const float*)nullptr,
                           (int)M, HID, DIN);
    } else {
        hipLaunchKernelGGL(gemm_nt<ushort_t>, dim3(M / BM, HID / BN), dim3(256), 0, stream,
                           batch_H, DIN, W_i2h, DIN, (ushort_t*)Hproj, HID, (const float*)nullptr,
                           (int)M, HID, DIN);
    }
    for (int s = 0; s < STEPS; ++s) {
        hipLaunchKernelGGL(gemm_nt<float>, dim3(BATCH / BM, 1024 / BN), dim3(256), 0, stream,
                           hiddenB, HID, Wcat, HID, hgB, 1024, bcatB, BATCH, 1024, HID);
        if (use_fp32) {
            hipLaunchKernelGGL(attn_step<float>, dim3(BATCH), dim3(256), 0, stream,
                               (const float*)Hproj, batch_H, hgB, W_score, context);
        } else {
            hipLaunchKernelGGL(attn_step<ushort_t>, dim3(BATCH), dim3(256), 0, stream,
                               (const ushort_t*)Hproj, batch_H, hgB, W_score, context);
        }
        hipLaunchKernelGGL(gemm_nt<float>, dim3(BATCH / BM, G3 / BN), dim3(256), 0, stream,
                           context, DIN, W_ih, GRUIN, gi, G3, b_ih, BATCH, G3, DIN);
        hipLaunchKernelGGL(gru_gate_gen, dim3(BATCH), dim3(HID), 0, stream,
                           gi, hgB, hiddenB, out, text, s, W_ih, W_gen, b_gen);
    }
}